// Round 1
// 349.342 us; speedup vs baseline: 1.0883x; 1.0883x over previous
//
#include <hip/hip_runtime.h>

// ---------- types / helpers ----------
typedef __attribute__((ext_vector_type(8))) short short8;   // 8 bf16 = 4 VGPRs
typedef __attribute__((ext_vector_type(4))) float f32x4;

__device__ __forceinline__ float bf2f(unsigned short u) {
    union { unsigned int i; float f; } x; x.i = ((unsigned int)u) << 16; return x.f;
}
__device__ __forceinline__ unsigned short f2bf(float f) {
    union { float f; unsigned int i; } x; x.f = f;
    unsigned int r = x.i + 0x7fffu + ((x.i >> 16) & 1u);   // RTNE
    return (unsigned short)(r >> 16);
}
__device__ __forceinline__ void async_copy16(const void* g, void* l) {
    __builtin_amdgcn_global_load_lds(
        (const __attribute__((address_space(1))) void*)g,
        (__attribute__((address_space(3))) void*)l,
        16, 0, 0);
}

// ---------- fp32 -> bf16 convert (x) ----------
__global__ __launch_bounds__(256) void conv_f32_bf16(const float* __restrict__ in,
                                                     unsigned short* __restrict__ out, int n) {
    int i = (blockIdx.x * 256 + threadIdx.x) * 4;
    if (i < n) {
        float4 v = *(const float4*)&in[i];
        ushort4 o;
        o.x = f2bf(v.x); o.y = f2bf(v.y); o.z = f2bf(v.z); o.w = f2bf(v.w);
        *(ushort4*)&out[i] = o;
    }
}

// ---------- transpose + convert: in (R x C fp32) -> out (C x R bf16) ----------
__global__ __launch_bounds__(256) void transpose_to_bf16(const float* __restrict__ in,
                                                         unsigned short* __restrict__ out,
                                                         int R, int C) {
    __shared__ float tile[32][33];
    int bx = blockIdx.x * 32;                      // C index
    int by = blockIdx.y * 32;                      // R index
    int tx = threadIdx.x & 31, ty = threadIdx.x >> 5;
    #pragma unroll
    for (int r = ty; r < 32; r += 8)
        tile[r][tx] = in[(size_t)(by + r) * C + bx + tx];
    __syncthreads();
    #pragma unroll
    for (int r = ty; r < 32; r += 8)
        out[(size_t)(bx + r) * R + by + tx] = f2bf(tile[tx][r]);
}

// ---------- bf16 GEMM: C[M,N] = A[M,K] * Bt[N,K]^T + bias ----------
// 256x256 tile, BK=64, 512 threads (8 waves 2x4), 8-phase schedule (4 phases/K-tile):
//   {ds_read frag subtile || issue 1 half-tile global_load_lds} -> s_barrier ->
//   lgkmcnt(0)+sched_barrier -> setprio(1) -> 16 MFMA -> setprio(0) -> s_barrier.
// Counted vmcnt(6) once per K-tile (3 half-tiles in flight), never 0 in main loop.
// LDS 128 KiB: [buf2][A/B][kk-half2][256 rows][32 cols] bf16, XOR swizzle
// chunk^=(row>>1)&3 applied to BOTH global source and ds_read (linear gload_lds dest).
template<bool OUT_BF16>
__global__ __launch_bounds__(512, 2) void gemm_bf16(const unsigned short* __restrict__ A, int lda,
                                                    const unsigned short* __restrict__ Bt, int ldb,
                                                    const float* __restrict__ bias,
                                                    void* __restrict__ C, int ldc, int K, int ntn) {
    __shared__ short smem[65536];   // 128 KiB

    const int tid  = threadIdx.x;
    const int lane = tid & 63;
    const int quad = lane >> 4;
    const int l16  = lane & 15;
    const int wid  = tid >> 6;
    const int wm   = wid >> 2;       // 0..1
    const int wn   = wid & 3;        // 0..3

    // XCD-aware bijective blockIdx swizzle (grids are % 8 == 0)
    const int nwg = gridDim.x;
    const int bid = blockIdx.x;
    const int wg  = (bid & 7) * (nwg >> 3) + (bid >> 3);
    const int m0  = (wg / ntn) * 256;
    const int n0  = (wg % ntn) * 256;

    const int NT = K >> 6;           // K-tiles (16 for K=1024)

    // per-thread staging source pointers: LDS chunk L = j*512+tid -> (r=L>>2, c=L&3),
    // source k-chunk cs = c ^ ((r>>1)&3)  [involution; read side applies same XOR]
    const unsigned short* aSrc[2];
    const unsigned short* bSrc[2];
    #pragma unroll
    for (int j = 0; j < 2; j++) {
        const int L  = j * 512 + tid;
        const int r  = L >> 2;
        const int cs = (L & 3) ^ ((r >> 1) & 3);
        aSrc[j] = A  + (size_t)(m0 + r) * lda + cs * 8;
        bSrc[j] = Bt + (size_t)(n0 + r) * ldb + cs * 8;
    }

#define STAGE_A(p, h, kofs) do { \
        short* d_ = smem + (p) * 32768 + (h) * 8192; \
        async_copy16(aSrc[0] + (kofs) + (h) * 32, d_ + tid * 8); \
        async_copy16(aSrc[1] + (kofs) + (h) * 32, d_ + (512 + tid) * 8); \
    } while (0)
#define STAGE_B(p, h, kofs) do { \
        short* d_ = smem + (p) * 32768 + 16384 + (h) * 8192; \
        async_copy16(bSrc[0] + (kofs) + (h) * 32, d_ + tid * 8); \
        async_copy16(bSrc[1] + (kofs) + (h) * 32, d_ + (512 + tid) * 8); \
    } while (0)

#define LDA_FRAG(dst, p, h, ibase) do { \
        const short* base_ = smem + (p) * 32768 + (h) * 8192; \
        _Pragma("unroll") \
        for (int i_ = 0; i_ < 4; i_++) { \
            const int row_ = wm * 128 + ((ibase) + i_) * 16 + l16; \
            dst[i_] = *(const short8*)&base_[row_ * 32 + ((quad ^ ((row_ >> 1) & 3)) * 8)]; \
        } \
    } while (0)
#define LDB_FRAG(dst, p, h) do { \
        const short* base_ = smem + (p) * 32768 + 16384 + (h) * 8192; \
        _Pragma("unroll") \
        for (int j_ = 0; j_ < 4; j_++) { \
            const int row_ = wn * 64 + j_ * 16 + l16; \
            dst[j_] = *(const short8*)&base_[row_ * 32 + ((quad ^ ((row_ >> 1) & 3)) * 8)]; \
        } \
    } while (0)

#define MFMA16(ib, av, bv) do { \
        _Pragma("unroll") \
        for (int i_ = 0; i_ < 4; i_++) \
            _Pragma("unroll") \
            for (int j_ = 0; j_ < 4; j_++) \
                acc[(ib) + i_][j_] = __builtin_amdgcn_mfma_f32_16x16x32_bf16(av[i_], bv[j_], acc[(ib) + i_][j_], 0, 0, 0); \
    } while (0)

#define PHASE_MID() do { \
        __builtin_amdgcn_s_barrier(); \
        asm volatile("s_waitcnt lgkmcnt(0)" ::: "memory"); \
        __builtin_amdgcn_sched_barrier(0); \
        __builtin_amdgcn_s_setprio(1); \
    } while (0)
#define PHASE_END() do { \
        __builtin_amdgcn_s_setprio(0); \
        __builtin_amdgcn_s_barrier(); \
    } while (0)

    f32x4 acc[8][4] = {};

    // ---- prologue: tile0 {A0,B0,A1,B1}; tile1 {A0,B0,A1}  (B1(1) issued in ph1 of t=0)
    STAGE_A(0, 0, 0);  STAGE_B(0, 0, 0);  STAGE_A(0, 1, 0);  STAGE_B(0, 1, 0);
    asm volatile("s_waitcnt vmcnt(4)" ::: "memory");
    STAGE_A(1, 0, 64); STAGE_B(1, 0, 64); STAGE_A(1, 1, 64);
    asm volatile("s_waitcnt vmcnt(6)" ::: "memory");   // tile0 fully landed, 3 halves in flight
    __builtin_amdgcn_s_barrier();

    for (int t = 0; t < NT; t++) {
        const int p  = t & 1;
        const int kn = (t + 2) * 64;
        short8 a[4], b[4], a2[4];

        // phase 1: h0, A rows 0-3 + B (8 reads); prefetch B1(t+1)
        LDA_FRAG(a, p, 0, 0);
        LDB_FRAG(b, p, 0);
        if (t + 1 < NT) STAGE_B(p ^ 1, 1, (t + 1) * 64);
        PHASE_MID();
        MFMA16(0, a, b);
        PHASE_END();

        // phase 2: h0, A rows 4-7 (4 reads); prefetch A0(t+2) (A-h0(t) just consumed)
        LDA_FRAG(a2, p, 0, 4);
        if (t + 2 < NT) STAGE_A(p, 0, kn);
        PHASE_MID();
        MFMA16(4, a2, b);
        PHASE_END();

        // phase 3: h1, A rows 0-3 + B (8 reads); prefetch B0(t+2) (B-h0(t) dead since ph1)
        LDA_FRAG(a, p, 1, 0);
        LDB_FRAG(b, p, 1);
        if (t + 2 < NT) STAGE_B(p, 0, kn);
        PHASE_MID();
        MFMA16(0, a, b);
        PHASE_END();

        // phase 4: h1, A rows 4-7 (4 reads); prefetch A1(t+2); counted vmcnt
        LDA_FRAG(a2, p, 1, 4);
        if (t + 2 < NT) STAGE_A(p, 1, kn);
        if (t < NT - 2)       asm volatile("s_waitcnt vmcnt(6)" ::: "memory");  // tile t+1 landed
        else if (t == NT - 2) asm volatile("s_waitcnt vmcnt(0)" ::: "memory");  // tail drain
        PHASE_MID();
        MFMA16(4, a2, b);
        PHASE_END();
    }

    // ---- epilogue. C/D layout: col = lane&15, row = quad*4 + r  [m89/m91]
    if (OUT_BF16) {
        __syncthreads();                               // full drain; reuse smem
        unsigned short* tile = (unsigned short*)smem;  // [128][264] padded
        unsigned short* Cp   = (unsigned short*)C;
        #pragma unroll
        for (int hm = 0; hm < 2; hm++) {
            if (wm == hm) {
                #pragma unroll
                for (int j = 0; j < 4; j++) {
                    const int tcol = wn * 64 + j * 16 + l16;
                    const float bv = bias[n0 + tcol];
                    #pragma unroll
                    for (int i = 0; i < 8; i++) {
                        const int trow = i * 16 + quad * 4;
                        #pragma unroll
                        for (int r = 0; r < 4; r++)
                            tile[(trow + r) * 264 + tcol] = f2bf(acc[i][j][r] + bv);
                    }
                }
            }
            __syncthreads();
            #pragma unroll
            for (int pp = 0; pp < 8; pp++) {
                const int row = pp * 16 + (tid >> 5);
                const int ch  = tid & 31;
                short8 v = *(const short8*)&tile[row * 264 + ch * 8];
                *(short8*)&Cp[(size_t)(m0 + hm * 128 + row) * ldc + n0 + ch * 8] = v;
            }
            __syncthreads();
        }
    } else {
        float* Cp = (float*)C;
        #pragma unroll
        for (int j = 0; j < 4; j++) {
            const int gcol = n0 + wn * 64 + j * 16 + l16;
            const float bv = bias[gcol];
            #pragma unroll
            for (int i = 0; i < 8; i++) {
                const int grow = m0 + wm * 128 + i * 16 + quad * 4;
                #pragma unroll
                for (int r = 0; r < 4; r++)
                    Cp[(size_t)(grow + r) * ldc + gcol] = acc[i][j][r] + bv;
            }
        }
    }
#undef STAGE_A
#undef STAGE_B
#undef LDA_FRAG
#undef LDB_FRAG
#undef MFMA16
#undef PHASE_MID
#undef PHASE_END
}

// ---------- per-row q/k norms + kv pool ----------
__global__ __launch_bounds__(256) void norm_kv(const unsigned short* __restrict__ qkv,
                                               float* __restrict__ rnq,
                                               float* __restrict__ kv) {
    __shared__ float kvbuf[1024];
    const int tid = threadIdx.x, lane = tid & 63, wv = tid >> 6;
    *(float4*)&kvbuf[tid * 4] = make_float4(0.f, 0.f, 0.f, 0.f);
    __syncthreads();

    const int row0 = blockIdx.x * 32 + wv * 8;
    float a[4][4] = {};

    for (int rr = 0; rr < 8; rr++) {
        const size_t base = (size_t)(row0 + rr) * 3072;
        float q2 = 0.f;
        #pragma unroll
        for (int c = 0; c < 4; c++) {
            ushort4 qu = *(const ushort4*)&qkv[base + c * 256 + lane * 4];
            float x0 = bf2f(qu.x), x1 = bf2f(qu.y), x2 = bf2f(qu.z), x3 = bf2f(qu.w);
            q2 += x0 * x0 + x1 * x1 + x2 * x2 + x3 * x3;
        }
        #pragma unroll
        for (int m = 32; m; m >>= 1) q2 += __shfl_xor(q2, m, 64);
        if (lane == 0) rnq[row0 + rr] = rsqrtf(q2);

        float k2 = 0.f;
        float kf[4][4];
        #pragma unroll
        for (int c = 0; c < 4; c++) {
            ushort4 ku = *(const ushort4*)&qkv[base + 1024 + c * 256 + lane * 4];
            kf[c][0] = bf2f(ku.x); kf[c][1] = bf2f(ku.y);
            kf[c][2] = bf2f(ku.z); kf[c][3] = bf2f(ku.w);
            k2 += kf[c][0]*kf[c][0] + kf[c][1]*kf[c][1] + kf[c][2]*kf[c][2] + kf[c][3]*kf[c][3];
        }
        #pragma unroll
        for (int m = 32; m; m >>= 1) k2 += __shfl_xor(k2, m, 64);
        const float rk = rsqrtf(k2);

        #pragma unroll
        for (int c = 0; c < 4; c++) {
            ushort4 vu = *(const ushort4*)&qkv[base + 2048 + c * 256 + lane * 4];
            a[c][0] += kf[c][0] * rk * bf2f(vu.x);
            a[c][1] += kf[c][1] * rk * bf2f(vu.y);
            a[c][2] += kf[c][2] * rk * bf2f(vu.z);
            a[c][3] += kf[c][3] * rk * bf2f(vu.w);
        }
    }
    #pragma unroll
    for (int c = 0; c < 4; c++)
        #pragma unroll
        for (int i = 0; i < 4; i++)
            atomicAdd(&kvbuf[c * 256 + lane * 4 + i], a[c][i]);
    __syncthreads();
    const int b = blockIdx.x >> 7;     // 128 blocks per batch (4096 rows / 32)
    #pragma unroll
    for (int i = 0; i < 4; i++)
        atomicAdd(&kv[b * 1024 + tid * 4 + i], kvbuf[tid * 4 + i]);
}

// ---------- out = q_hat * kv  (written into qkv's dead v-region, bf16) ----------
__global__ __launch_bounds__(256) void scale_q(unsigned short* __restrict__ qkv,
                                               const float* __restrict__ rnq,
                                               const float* __restrict__ kv, int T) {
    const int t = blockIdx.x;
    const int b = t / T;
    const int d = threadIdx.x * 4;
    const float rq = rnq[t];
    const size_t base = (size_t)t * 3072;
    ushort4 qu = *(const ushort4*)&qkv[base + d];
    float4 kvv = *(const float4*)&kv[b * 1024 + d];
    ushort4 o;
    o.x = f2bf(bf2f(qu.x) * rq * kvv.x);
    o.y = f2bf(bf2f(qu.y) * rq * kvv.y);
    o.z = f2bf(bf2f(qu.z) * rq * kvv.z);
    o.w = f2bf(bf2f(qu.w) * rq * kvv.w);
    *(ushort4*)&qkv[base + 2048 + d] = o;
}

extern "C" void kernel_launch(void* const* d_in, const int* in_sizes, int n_in,
                              void* d_out, int out_size, void* d_ws, size_t ws_size,
                              hipStream_t stream) {
    const float* x    = (const float*)d_in[0];   // (4,4096,1024)
    const float* Wqkv = (const float*)d_in[1];   // (1024,3072)
    const float* bqkv = (const float*)d_in[2];   // (3072)
    const float* Wout = (const float*)d_in[3];   // (1024,1024)
    const float* bout = (const float*)d_in[4];   // (1024)
    float* out = (float*)d_out;                  // (4,4096,1024) fp32

    // workspace layout (~136 MB)
    char* ws = (char*)d_ws;
    unsigned short* x_bf  = (unsigned short*)(ws + 0);           // 32 MB
    unsigned short* WqkvT = (unsigned short*)(ws + 33554432);    // 6 MB
    unsigned short* WoutT = (unsigned short*)(ws + 39845888);    // 2 MB
    unsigned short* qkv   = (unsigned short*)(ws + 41943040);    // 96 MB
    float* rnq            = (float*)(ws + 142606336);            // 64 KB
    float* kv             = (float*)(ws + 142671872);            // 16 KB

    conv_f32_bf16<<<16384, 256, 0, stream>>>(x, x_bf, 16777216);
    transpose_to_bf16<<<dim3(96, 32), 256, 0, stream>>>(Wqkv, WqkvT, 1024, 3072);
    transpose_to_bf16<<<dim3(32, 32), 256, 0, stream>>>(Wout, WoutT, 1024, 1024);

    // qkv = x @ Wqkv + bqkv   (M=16384, N=3072, K=1024) -> bf16; 64x12 = 768 tiles
    gemm_bf16<true><<<768, 512, 0, stream>>>(x_bf, 1024, WqkvT, 1024, bqkv,
                                             (void*)qkv, 3072, 1024, 12);

    hipMemsetAsync(kv, 0, 4096 * sizeof(float), stream);
    norm_kv<<<512, 256, 0, stream>>>(qkv, rnq, kv);

    scale_q<<<16384, 256, 0, stream>>>(qkv, rnq, kv, 4096);

    // y = out @ Wout + bout   (M=16384, N=1024, K=1024) -> fp32 d_out; 64x4 = 256 tiles
    gemm_bf16<false><<<256, 512, 0, stream>>>(qkv + 2048, 3072, WoutT, 1024, bout,
                                              (void*)out, 1024, 1024, 4);
}

// Round 2
// 345.413 us; speedup vs baseline: 1.1007x; 1.0114x over previous
//
#include <hip/hip_runtime.h>

// ---------- types / helpers ----------
typedef __attribute__((ext_vector_type(8))) short short8;   // 8 bf16 = 4 VGPRs
typedef __attribute__((ext_vector_type(4))) float f32x4;

__device__ __forceinline__ float bf2f(unsigned short u) {
    union { unsigned int i; float f; } x; x.i = ((unsigned int)u) << 16; return x.f;
}
__device__ __forceinline__ unsigned short f2bf(float f) {
    union { float f; unsigned int i; } x; x.f = f;
    unsigned int r = x.i + 0x7fffu + ((x.i >> 16) & 1u);   // RTNE
    return (unsigned short)(r >> 16);
}
__device__ __forceinline__ void async_copy16(const void* g, void* l) {
    __builtin_amdgcn_global_load_lds(
        (const __attribute__((address_space(1))) void*)g,
        (__attribute__((address_space(3))) void*)l,
        16, 0, 0);
}

// ---------- fp32 -> bf16 convert (x) ----------
__global__ __launch_bounds__(256) void conv_f32_bf16(const float* __restrict__ in,
                                                     unsigned short* __restrict__ out, int n) {
    int i = (blockIdx.x * 256 + threadIdx.x) * 4;
    if (i < n) {
        float4 v = *(const float4*)&in[i];
        ushort4 o;
        o.x = f2bf(v.x); o.y = f2bf(v.y); o.z = f2bf(v.z); o.w = f2bf(v.w);
        *(ushort4*)&out[i] = o;
    }
}

// ---------- transpose + convert: in (R x C fp32) -> out (C x R bf16) ----------
__global__ __launch_bounds__(256) void transpose_to_bf16(const float* __restrict__ in,
                                                         unsigned short* __restrict__ out,
                                                         int R, int C) {
    __shared__ float tile[32][33];
    int bx = blockIdx.x * 32;                      // C index
    int by = blockIdx.y * 32;                      // R index
    int tx = threadIdx.x & 31, ty = threadIdx.x >> 5;
    #pragma unroll
    for (int r = ty; r < 32; r += 8)
        tile[r][tx] = in[(size_t)(by + r) * C + bx + tx];
    __syncthreads();
    #pragma unroll
    for (int r = ty; r < 32; r += 8)
        out[(size_t)(bx + r) * R + by + tx] = f2bf(tile[tx][r]);
}

// ---------- bf16 GEMM: C[M,N] = A[M,K] * Bt[N,K]^T + bias ----------
// 256x256 tile, BK=64, 512 threads (8 waves 2x4), 8-phase/2-K-tile schedule.
// Round-2 change: ALL LDS read addresses = 4 hoisted per-lane base pointers
// (pA0/pA1/pB0/pB1) + compile-time immediate offsets; staging = 4 incremented
// global pointers + constant offsets; K-loop unrolled x2 so buffer parity is a
// literal. Swizzle identity: (row>>1)&3 == (l16>>1)&3 (no bit overlap in
// row = wbase + i*16 + l16), so the XOR chunk is per-lane constant.
// vmcnt(6) once per K-tile (3 half-tiles in flight), never 0 in main loop.
template<bool OUT_BF16>
__global__ __launch_bounds__(512, 2) void gemm_bf16(const unsigned short* __restrict__ A, int lda,
                                                    const unsigned short* __restrict__ Bt, int ldb,
                                                    const float* __restrict__ bias,
                                                    void* __restrict__ C, int ldc, int K, int ntn) {
    __shared__ short smem[65536];   // 128 KiB

    const int tid  = threadIdx.x;
    const int lane = tid & 63;
    const int quad = lane >> 4;
    const int l16  = lane & 15;
    const int wid  = tid >> 6;
    const int wm   = wid >> 2;       // 0..1
    const int wn   = wid & 3;        // 0..3

    // XCD-aware bijective blockIdx swizzle (grids are % 8 == 0)
    const int nwg = gridDim.x;
    const int bid = blockIdx.x;
    const int wg  = (bid & 7) * (nwg >> 3) + (bid >> 3);
    const int m0  = (wg / ntn) * 256;
    const int n0  = (wg % ntn) * 256;

    const int NT = K >> 6;           // K-tiles (16 for K=1024); must be even >= 4

    // ---- hoisted LDS read bases (shorts). Swizzle chunk SW = quad ^ ((l16>>1)&3).
    const int SW8  = (quad ^ ((l16 >> 1) & 3)) * 8;
    const int offA = (wm * 128 + l16) * 32 + SW8;
    const int offB = 16384 + (wn * 64 + l16) * 32 + SW8;
    const short* pA0 = smem + offA;
    const short* pA1 = smem + 32768 + offA;
    const short* pB0 = smem + offB;
    const short* pB1 = smem + 32768 + offB;

    // ---- staging source pointers (advance by 64 shorts per K-tile, 128 per pair)
    // LDS chunk L = j*512+tid -> (r=L>>2, c=L&3), source k-chunk cs = c ^ ((r>>1)&3)
    const unsigned short *aS0, *aS1, *bS0, *bS1;
    {
        const int L0  = tid,        r0 = L0 >> 2, c0 = (L0 & 3) ^ ((r0 >> 1) & 3);
        const int L1  = 512 + tid,  r1 = L1 >> 2, c1 = (L1 & 3) ^ ((r1 >> 1) & 3);
        aS0 = A  + (size_t)(m0 + r0) * lda + c0 * 8;
        aS1 = A  + (size_t)(m0 + r1) * lda + c1 * 8;
        bS0 = Bt + (size_t)(n0 + r0) * ldb + c0 * 8;
        bS1 = Bt + (size_t)(n0 + r1) * ldb + c1 * 8;
    }
    const int dstoff = tid * 8;      // shorts (lane x 16B, linear gload_lds dest)

#define STAGE(BUF, ISB, H, AH) do { \
        short* d_ = smem + (BUF) * 32768 + (ISB) * 16384 + (H) * 8192 + dstoff; \
        async_copy16(((ISB) ? bS0 : aS0) + (AH) * 64 + (H) * 32, d_); \
        async_copy16(((ISB) ? bS1 : aS1) + (AH) * 64 + (H) * 32, d_ + 4096); \
    } while (0)

#define RDA(dst, P, H, IB) do { \
        dst[0] = *(const short8*)(pA##P + ((IB) + 0) * 512 + (H) * 8192); \
        dst[1] = *(const short8*)(pA##P + ((IB) + 1) * 512 + (H) * 8192); \
        dst[2] = *(const short8*)(pA##P + ((IB) + 2) * 512 + (H) * 8192); \
        dst[3] = *(const short8*)(pA##P + ((IB) + 3) * 512 + (H) * 8192); \
    } while (0)
#define RDB(dst, P, H) do { \
        dst[0] = *(const short8*)(pB##P + 0 * 512 + (H) * 8192); \
        dst[1] = *(const short8*)(pB##P + 1 * 512 + (H) * 8192); \
        dst[2] = *(const short8*)(pB##P + 2 * 512 + (H) * 8192); \
        dst[3] = *(const short8*)(pB##P + 3 * 512 + (H) * 8192); \
    } while (0)

#define MFMA16(ib, av, bv) do { \
        _Pragma("unroll") \
        for (int i_ = 0; i_ < 4; i_++) \
            _Pragma("unroll") \
            for (int j_ = 0; j_ < 4; j_++) \
                acc[(ib) + i_][j_] = __builtin_amdgcn_mfma_f32_16x16x32_bf16(av[i_], bv[j_], acc[(ib) + i_][j_], 0, 0, 0); \
    } while (0)

#define PH_MID() do { \
        __builtin_amdgcn_s_barrier(); \
        asm volatile("s_waitcnt lgkmcnt(0)" ::: "memory"); \
        __builtin_amdgcn_s_setprio(1); \
    } while (0)
#define PH_END() do { \
        __builtin_amdgcn_s_setprio(0); \
        __builtin_amdgcn_s_barrier(); \
    } while (0)

#define VM6   asm volatile("s_waitcnt vmcnt(6)" ::: "memory")
#define VM0   asm volatile("s_waitcnt vmcnt(0)" ::: "memory")
#define VMNOP ((void)0)

// One K-tile = 4 phases. P = buffer parity (literal), AH = source base tile
// offset (pointers advance per pair), T1 = stage B1(t+1), T2 = stage t+2.
#define KTILE(P, AH, T1, T2, VMW) do { \
        short8 a[4], b[4], a2[4]; \
        /* phase 1: A h0 rows0-3 + B h0 (8 reads); prefetch B1(t+1) */ \
        RDA(a, P, 0, 0); RDB(b, P, 0); \
        if (T1) STAGE((P) ^ 1, 1, 1, (AH) + 1); \
        PH_MID(); MFMA16(0, a, b); PH_END(); \
        /* phase 2: A h0 rows4-7 (4 reads); prefetch A0(t+2) */ \
        RDA(a2, P, 0, 4); \
        if (T2) STAGE(P, 0, 0, (AH) + 2); \
        PH_MID(); MFMA16(4, a2, b); PH_END(); \
        /* phase 3: A h1 rows0-3 + B h1 (8 reads); prefetch B0(t+2) */ \
        RDA(a, P, 1, 0); RDB(b, P, 1); \
        if (T2) STAGE(P, 1, 0, (AH) + 2); \
        PH_MID(); MFMA16(0, a, b); PH_END(); \
        /* phase 4: A h1 rows4-7 (4 reads); prefetch A1(t+2); counted vmcnt */ \
        RDA(a2, P, 1, 4); \
        if (T2) STAGE(P, 0, 1, (AH) + 2); \
        VMW; \
        PH_MID(); MFMA16(4, a2, b); PH_END(); \
    } while (0)

    f32x4 acc[8][4] = {};

    // ---- prologue: tile0 {A0,B0,A1,B1}; tile1 {A0,B0,A1} (B1(1) issued in ph1 of t=0)
    STAGE(0, 0, 0, 0); STAGE(0, 1, 0, 0); STAGE(0, 0, 1, 0); STAGE(0, 1, 1, 0);
    asm volatile("s_waitcnt vmcnt(4)" ::: "memory");
    STAGE(1, 0, 0, 1); STAGE(1, 1, 0, 1); STAGE(1, 0, 1, 1);
    asm volatile("s_waitcnt vmcnt(6)" ::: "memory");   // tile0 fully landed, 3 halves in flight
    __builtin_amdgcn_s_barrier();

    // ---- main loop: pairs of K-tiles (8 phases), tiles 0..NT-3
    for (int u = 0; u + 3 < NT; u += 2) {
        KTILE(0, 0, 1, 1, VM6);
        KTILE(1, 1, 1, 1, VM6);
        aS0 += 128; aS1 += 128; bS0 += 128; bS1 += 128;
    }
    // ---- tail: tile NT-2 (stage B1(NT-1) only, full drain), tile NT-1 (pure compute)
    KTILE(0, 0, 1, 0, VM0);
    KTILE(1, 1, 0, 0, VMNOP);

    // ---- epilogue. C/D layout: col = lane&15, row = quad*4 + r  [m89/m91]
    if (OUT_BF16) {
        __syncthreads();                               // full drain; reuse smem
        unsigned short* tile = (unsigned short*)smem;  // [128][264] padded
        unsigned short* Cp   = (unsigned short*)C;
        #pragma unroll
        for (int hm = 0; hm < 2; hm++) {
            if (wm == hm) {
                #pragma unroll
                for (int j = 0; j < 4; j++) {
                    const int tcol = wn * 64 + j * 16 + l16;
                    const float bv = bias[n0 + tcol];
                    #pragma unroll
                    for (int i = 0; i < 8; i++) {
                        const int trow = i * 16 + quad * 4;
                        #pragma unroll
                        for (int r = 0; r < 4; r++)
                            tile[(trow + r) * 264 + tcol] = f2bf(acc[i][j][r] + bv);
                    }
                }
            }
            __syncthreads();
            #pragma unroll
            for (int pp = 0; pp < 8; pp++) {
                const int row = pp * 16 + (tid >> 5);
                const int ch  = tid & 31;
                short8 v = *(const short8*)&tile[row * 264 + ch * 8];
                *(short8*)&Cp[(size_t)(m0 + hm * 128 + row) * ldc + n0 + ch * 8] = v;
            }
            __syncthreads();
        }
    } else {
        float* Cp = (float*)C;
        #pragma unroll
        for (int j = 0; j < 4; j++) {
            const int gcol = n0 + wn * 64 + j * 16 + l16;
            const float bv = bias[gcol];
            #pragma unroll
            for (int i = 0; i < 8; i++) {
                const int grow = m0 + wm * 128 + i * 16 + quad * 4;
                #pragma unroll
                for (int r = 0; r < 4; r++)
                    Cp[(size_t)(grow + r) * ldc + gcol] = acc[i][j][r] + bv;
            }
        }
    }
#undef STAGE
#undef RDA
#undef RDB
#undef MFMA16
#undef PH_MID
#undef PH_END
#undef VM6
#undef VM0
#undef VMNOP
#undef KTILE
}

// ---------- per-row q/k norms + kv pool ----------
__global__ __launch_bounds__(256) void norm_kv(const unsigned short* __restrict__ qkv,
                                               float* __restrict__ rnq,
                                               float* __restrict__ kv) {
    __shared__ float kvbuf[1024];
    const int tid = threadIdx.x, lane = tid & 63, wv = tid >> 6;
    *(float4*)&kvbuf[tid * 4] = make_float4(0.f, 0.f, 0.f, 0.f);
    __syncthreads();

    const int row0 = blockIdx.x * 32 + wv * 8;
    float a[4][4] = {};

    for (int rr = 0; rr < 8; rr++) {
        const size_t base = (size_t)(row0 + rr) * 3072;
        float q2 = 0.f;
        #pragma unroll
        for (int c = 0; c < 4; c++) {
            ushort4 qu = *(const ushort4*)&qkv[base + c * 256 + lane * 4];
            float x0 = bf2f(qu.x), x1 = bf2f(qu.y), x2 = bf2f(qu.z), x3 = bf2f(qu.w);
            q2 += x0 * x0 + x1 * x1 + x2 * x2 + x3 * x3;
        }
        #pragma unroll
        for (int m = 32; m; m >>= 1) q2 += __shfl_xor(q2, m, 64);
        if (lane == 0) rnq[row0 + rr] = rsqrtf(q2);

        float k2 = 0.f;
        float kf[4][4];
        #pragma unroll
        for (int c = 0; c < 4; c++) {
            ushort4 ku = *(const ushort4*)&qkv[base + 1024 + c * 256 + lane * 4];
            kf[c][0] = bf2f(ku.x); kf[c][1] = bf2f(ku.y);
            kf[c][2] = bf2f(ku.z); kf[c][3] = bf2f(ku.w);
            k2 += kf[c][0]*kf[c][0] + kf[c][1]*kf[c][1] + kf[c][2]*kf[c][2] + kf[c][3]*kf[c][3];
        }
        #pragma unroll
        for (int m = 32; m; m >>= 1) k2 += __shfl_xor(k2, m, 64);
        const float rk = rsqrtf(k2);

        #pragma unroll
        for (int c = 0; c < 4; c++) {
            ushort4 vu = *(const ushort4*)&qkv[base + 2048 + c * 256 + lane * 4];
            a[c][0] += kf[c][0] * rk * bf2f(vu.x);
            a[c][1] += kf[c][1] * rk * bf2f(vu.y);
            a[c][2] += kf[c][2] * rk * bf2f(vu.z);
            a[c][3] += kf[c][3] * rk * bf2f(vu.w);
        }
    }
    #pragma unroll
    for (int c = 0; c < 4; c++)
        #pragma unroll
        for (int i = 0; i < 4; i++)
            atomicAdd(&kvbuf[c * 256 + lane * 4 + i], a[c][i]);
    __syncthreads();
    const int b = blockIdx.x >> 7;     // 128 blocks per batch (4096 rows / 32)
    #pragma unroll
    for (int i = 0; i < 4; i++)
        atomicAdd(&kv[b * 1024 + tid * 4 + i], kvbuf[tid * 4 + i]);
}

// ---------- out = q_hat * kv  (written into qkv's dead v-region, bf16) ----------
__global__ __launch_bounds__(256) void scale_q(unsigned short* __restrict__ qkv,
                                               const float* __restrict__ rnq,
                                               const float* __restrict__ kv, int T) {
    const int t = blockIdx.x;
    const int b = t / T;
    const int d = threadIdx.x * 4;
    const float rq = rnq[t];
    const size_t base = (size_t)t * 3072;
    ushort4 qu = *(const ushort4*)&qkv[base + d];
    float4 kvv = *(const float4*)&kv[b * 1024 + d];
    ushort4 o;
    o.x = f2bf(bf2f(qu.x) * rq * kvv.x);
    o.y = f2bf(bf2f(qu.y) * rq * kvv.y);
    o.z = f2bf(bf2f(qu.z) * rq * kvv.z);
    o.w = f2bf(bf2f(qu.w) * rq * kvv.w);
    *(ushort4*)&qkv[base + 2048 + d] = o;
}

extern "C" void kernel_launch(void* const* d_in, const int* in_sizes, int n_in,
                              void* d_out, int out_size, void* d_ws, size_t ws_size,
                              hipStream_t stream) {
    const float* x    = (const float*)d_in[0];   // (4,4096,1024)
    const float* Wqkv = (const float*)d_in[1];   // (1024,3072)
    const float* bqkv = (const float*)d_in[2];   // (3072)
    const float* Wout = (const float*)d_in[3];   // (1024,1024)
    const float* bout = (const float*)d_in[4];   // (1024)
    float* out = (float*)d_out;                  // (4,4096,1024) fp32

    // workspace layout (~136 MB)
    char* ws = (char*)d_ws;
    unsigned short* x_bf  = (unsigned short*)(ws + 0);           // 32 MB
    unsigned short* WqkvT = (unsigned short*)(ws + 33554432);    // 6 MB
    unsigned short* WoutT = (unsigned short*)(ws + 39845888);    // 2 MB
    unsigned short* qkv   = (unsigned short*)(ws + 41943040);    // 96 MB
    float* rnq            = (float*)(ws + 142606336);            // 64 KB
    float* kv             = (float*)(ws + 142671872);            // 16 KB

    conv_f32_bf16<<<16384, 256, 0, stream>>>(x, x_bf, 16777216);
    transpose_to_bf16<<<dim3(96, 32), 256, 0, stream>>>(Wqkv, WqkvT, 1024, 3072);
    transpose_to_bf16<<<dim3(32, 32), 256, 0, stream>>>(Wout, WoutT, 1024, 1024);

    // qkv = x @ Wqkv + bqkv   (M=16384, N=3072, K=1024) -> bf16; 64x12 = 768 tiles
    gemm_bf16<true><<<768, 512, 0, stream>>>(x_bf, 1024, WqkvT, 1024, bqkv,
                                             (void*)qkv, 3072, 1024, 12);

    hipMemsetAsync(kv, 0, 4096 * sizeof(float), stream);
    norm_kv<<<512, 256, 0, stream>>>(qkv, rnq, kv);

    scale_q<<<16384, 256, 0, stream>>>(qkv, rnq, kv, 4096);

    // y = out @ Wout + bout   (M=16384, N=1024, K=1024) -> fp32 d_out; 64x4 = 256 tiles
    gemm_bf16<false><<<256, 512, 0, stream>>>(qkv + 2048, 3072, WoutT, 1024, bout,
                                              (void*)out, 1024, 1024, 4);
}

// Round 3
// 332.356 us; speedup vs baseline: 1.1439x; 1.0393x over previous
//
#include <hip/hip_runtime.h>

// ---------- types / helpers ----------
typedef __attribute__((ext_vector_type(8))) short short8;   // 8 bf16 = 4 VGPRs
typedef __attribute__((ext_vector_type(4))) float f32x4;

__device__ __forceinline__ float bf2f(unsigned short u) {
    union { unsigned int i; float f; } x; x.i = ((unsigned int)u) << 16; return x.f;
}
__device__ __forceinline__ unsigned short f2bf(float f) {
    union { float f; unsigned int i; } x; x.f = f;
    unsigned int r = x.i + 0x7fffu + ((x.i >> 16) & 1u);   // RTNE
    return (unsigned short)(r >> 16);
}
__device__ __forceinline__ void async_copy16(const void* g, void* l) {
    __builtin_amdgcn_global_load_lds(
        (const __attribute__((address_space(1))) void*)g,
        (__attribute__((address_space(3))) void*)l,
        16, 0, 0);
}

// ---------- fp32 -> bf16 convert (x) ----------
__global__ __launch_bounds__(256) void conv_f32_bf16(const float* __restrict__ in,
                                                     unsigned short* __restrict__ out, int n) {
    int i = (blockIdx.x * 256 + threadIdx.x) * 4;
    if (i < n) {
        float4 v = *(const float4*)&in[i];
        ushort4 o;
        o.x = f2bf(v.x); o.y = f2bf(v.y); o.z = f2bf(v.z); o.w = f2bf(v.w);
        *(ushort4*)&out[i] = o;
    }
}

// ---------- transpose + convert: in (R x C fp32) -> out (C x R bf16) ----------
__global__ __launch_bounds__(256) void transpose_to_bf16(const float* __restrict__ in,
                                                         unsigned short* __restrict__ out,
                                                         int R, int C) {
    __shared__ float tile[32][33];
    int bx = blockIdx.x * 32;                      // C index
    int by = blockIdx.y * 32;                      // R index
    int tx = threadIdx.x & 31, ty = threadIdx.x >> 5;
    #pragma unroll
    for (int r = ty; r < 32; r += 8)
        tile[r][tx] = in[(size_t)(by + r) * C + bx + tx];
    __syncthreads();
    #pragma unroll
    for (int r = ty; r < 32; r += 8)
        out[(size_t)(bx + r) * R + by + tx] = f2bf(tile[tx][r]);
}

// ---------- bf16 GEMM: C[M,N] = A[M,K] * Bt[N,K]^T + bias ----------
// 256x256 tile, BK=64, 512 threads (8 waves 2x4), 8-phase/2-K-tile schedule.
// Round-3 change: NO explicit lgkmcnt(0) after the phase barrier — compiler
// emits stepped lgkmcnt(N) waits per MFMA operand, so early waves start MFMA
// while the LDS pipe still drains later waves' reads (breaks the CU-wide
// drain->compute serialization that held MfmaUtil at 39%). ds_read issue is
// B-before-A so the first MFMA cluster's operands complete first.
// vmcnt(6) once per K-tile (3 half-tiles in flight), never 0 in main loop;
// the vmcnt asm memory-clobbers still pin all LDS ops at tile boundaries.
template<bool OUT_BF16>
__global__ __launch_bounds__(512, 2) void gemm_bf16(const unsigned short* __restrict__ A, int lda,
                                                    const unsigned short* __restrict__ Bt, int ldb,
                                                    const float* __restrict__ bias,
                                                    void* __restrict__ C, int ldc, int K, int ntn) {
    __shared__ short smem[65536];   // 128 KiB

    const int tid  = threadIdx.x;
    const int lane = tid & 63;
    const int quad = lane >> 4;
    const int l16  = lane & 15;
    const int wid  = tid >> 6;
    const int wm   = wid >> 2;       // 0..1
    const int wn   = wid & 3;        // 0..3

    // XCD-aware bijective blockIdx swizzle (grids are % 8 == 0)
    const int nwg = gridDim.x;
    const int bid = blockIdx.x;
    const int wg  = (bid & 7) * (nwg >> 3) + (bid >> 3);
    const int m0  = (wg / ntn) * 256;
    const int n0  = (wg % ntn) * 256;

    const int NT = K >> 6;           // K-tiles (16 for K=1024); must be even >= 4

    // ---- hoisted LDS read bases (shorts). Swizzle chunk SW = quad ^ ((l16>>1)&3).
    const int SW8  = (quad ^ ((l16 >> 1) & 3)) * 8;
    const int offA = (wm * 128 + l16) * 32 + SW8;
    const int offB = 16384 + (wn * 64 + l16) * 32 + SW8;
    const short* pA0 = smem + offA;
    const short* pA1 = smem + 32768 + offA;
    const short* pB0 = smem + offB;
    const short* pB1 = smem + 32768 + offB;

    // ---- staging source pointers (advance by 64 shorts per K-tile, 128 per pair)
    // LDS chunk L = j*512+tid -> (r=L>>2, c=L&3), source k-chunk cs = c ^ ((r>>1)&3)
    const unsigned short *aS0, *aS1, *bS0, *bS1;
    {
        const int L0  = tid,        r0 = L0 >> 2, c0 = (L0 & 3) ^ ((r0 >> 1) & 3);
        const int L1  = 512 + tid,  r1 = L1 >> 2, c1 = (L1 & 3) ^ ((r1 >> 1) & 3);
        aS0 = A  + (size_t)(m0 + r0) * lda + c0 * 8;
        aS1 = A  + (size_t)(m0 + r1) * lda + c1 * 8;
        bS0 = Bt + (size_t)(n0 + r0) * ldb + c0 * 8;
        bS1 = Bt + (size_t)(n0 + r1) * ldb + c1 * 8;
    }
    const int dstoff = tid * 8;      // shorts (lane x 16B, linear gload_lds dest)

#define STAGE(BUF, ISB, H, AH) do { \
        short* d_ = smem + (BUF) * 32768 + (ISB) * 16384 + (H) * 8192 + dstoff; \
        async_copy16(((ISB) ? bS0 : aS0) + (AH) * 64 + (H) * 32, d_); \
        async_copy16(((ISB) ? bS1 : aS1) + (AH) * 64 + (H) * 32, d_ + 4096); \
    } while (0)

#define RDA(dst, P, H, IB) do { \
        dst[0] = *(const short8*)(pA##P + ((IB) + 0) * 512 + (H) * 8192); \
        dst[1] = *(const short8*)(pA##P + ((IB) + 1) * 512 + (H) * 8192); \
        dst[2] = *(const short8*)(pA##P + ((IB) + 2) * 512 + (H) * 8192); \
        dst[3] = *(const short8*)(pA##P + ((IB) + 3) * 512 + (H) * 8192); \
    } while (0)
#define RDB(dst, P, H) do { \
        dst[0] = *(const short8*)(pB##P + 0 * 512 + (H) * 8192); \
        dst[1] = *(const short8*)(pB##P + 1 * 512 + (H) * 8192); \
        dst[2] = *(const short8*)(pB##P + 2 * 512 + (H) * 8192); \
        dst[3] = *(const short8*)(pB##P + 3 * 512 + (H) * 8192); \
    } while (0)

#define MFMA16(ib, av, bv) do { \
        _Pragma("unroll") \
        for (int i_ = 0; i_ < 4; i_++) \
            _Pragma("unroll") \
            for (int j_ = 0; j_ < 4; j_++) \
                acc[(ib) + i_][j_] = __builtin_amdgcn_mfma_f32_16x16x32_bf16(av[i_], bv[j_], acc[(ib) + i_][j_], 0, 0, 0); \
    } while (0)

// Round-3: barrier only; NO lgkmcnt(0) — compiler emits stepped per-operand
// lgkmcnt waits so MFMA overlaps the CU-wide LDS drain.
#define PH_MID() do { \
        __builtin_amdgcn_s_barrier(); \
        __builtin_amdgcn_s_setprio(1); \
    } while (0)
#define PH_END() do { \
        __builtin_amdgcn_s_setprio(0); \
        __builtin_amdgcn_s_barrier(); \
    } while (0)

#define VM6   asm volatile("s_waitcnt vmcnt(6)" ::: "memory")
#define VM0   asm volatile("s_waitcnt vmcnt(0)" ::: "memory")
#define VMNOP ((void)0)

// One K-tile = 4 phases. P = buffer parity (literal), AH = source base tile
// offset (pointers advance per pair), T1 = stage B1(t+1), T2 = stage t+2.
#define KTILE(P, AH, T1, T2, VMW) do { \
        short8 a[4], b[4], a2[4]; \
        /* phase 1: B h0 then A h0 rows0-3 (8 reads); prefetch B1(t+1) */ \
        RDB(b, P, 0); RDA(a, P, 0, 0); \
        if (T1) STAGE((P) ^ 1, 1, 1, (AH) + 1); \
        PH_MID(); MFMA16(0, a, b); PH_END(); \
        /* phase 2: A h0 rows4-7 (4 reads); prefetch A0(t+2) */ \
        RDA(a2, P, 0, 4); \
        if (T2) STAGE(P, 0, 0, (AH) + 2); \
        PH_MID(); MFMA16(4, a2, b); PH_END(); \
        /* phase 3: B h1 then A h1 rows0-3 (8 reads); prefetch B0(t+2) */ \
        RDB(b, P, 1); RDA(a, P, 1, 0); \
        if (T2) STAGE(P, 1, 0, (AH) + 2); \
        PH_MID(); MFMA16(0, a, b); PH_END(); \
        /* phase 4: A h1 rows4-7 (4 reads); prefetch A1(t+2); counted vmcnt */ \
        RDA(a2, P, 1, 4); \
        if (T2) STAGE(P, 0, 1, (AH) + 2); \
        VMW; \
        PH_MID(); MFMA16(4, a2, b); PH_END(); \
    } while (0)

    f32x4 acc[8][4] = {};

    // ---- prologue: tile0 {A0,B0,A1,B1}; tile1 {A0,B0,A1} (B1(1) issued in ph1 of t=0)
    STAGE(0, 0, 0, 0); STAGE(0, 1, 0, 0); STAGE(0, 0, 1, 0); STAGE(0, 1, 1, 0);
    asm volatile("s_waitcnt vmcnt(4)" ::: "memory");
    STAGE(1, 0, 0, 1); STAGE(1, 1, 0, 1); STAGE(1, 0, 1, 1);
    asm volatile("s_waitcnt vmcnt(6)" ::: "memory");   // tile0 fully landed, 3 halves in flight
    __builtin_amdgcn_s_barrier();

    // ---- main loop: pairs of K-tiles (8 phases), tiles 0..NT-3
    for (int u = 0; u + 3 < NT; u += 2) {
        KTILE(0, 0, 1, 1, VM6);
        KTILE(1, 1, 1, 1, VM6);
        aS0 += 128; aS1 += 128; bS0 += 128; bS1 += 128;
    }
    // ---- tail: tile NT-2 (stage B1(NT-1) only, full drain), tile NT-1 (pure compute)
    KTILE(0, 0, 1, 0, VM0);
    KTILE(1, 1, 0, 0, VMNOP);

    // ---- epilogue. C/D layout: col = lane&15, row = quad*4 + r  [m89/m91]
    if (OUT_BF16) {
        __syncthreads();                               // full drain; reuse smem
        unsigned short* tile = (unsigned short*)smem;  // [128][264] padded
        unsigned short* Cp   = (unsigned short*)C;
        #pragma unroll
        for (int hm = 0; hm < 2; hm++) {
            if (wm == hm) {
                #pragma unroll
                for (int j = 0; j < 4; j++) {
                    const int tcol = wn * 64 + j * 16 + l16;
                    const float bv = bias[n0 + tcol];
                    #pragma unroll
                    for (int i = 0; i < 8; i++) {
                        const int trow = i * 16 + quad * 4;
                        #pragma unroll
                        for (int r = 0; r < 4; r++)
                            tile[(trow + r) * 264 + tcol] = f2bf(acc[i][j][r] + bv);
                    }
                }
            }
            __syncthreads();
            #pragma unroll
            for (int pp = 0; pp < 8; pp++) {
                const int row = pp * 16 + (tid >> 5);
                const int ch  = tid & 31;
                short8 v = *(const short8*)&tile[row * 264 + ch * 8];
                *(short8*)&Cp[(size_t)(m0 + hm * 128 + row) * ldc + n0 + ch * 8] = v;
            }
            __syncthreads();
        }
    } else {
        float* Cp = (float*)C;
        #pragma unroll
        for (int j = 0; j < 4; j++) {
            const int gcol = n0 + wn * 64 + j * 16 + l16;
            const float bv = bias[gcol];
            #pragma unroll
            for (int i = 0; i < 8; i++) {
                const int grow = m0 + wm * 128 + i * 16 + quad * 4;
                #pragma unroll
                for (int r = 0; r < 4; r++)
                    Cp[(size_t)(grow + r) * ldc + gcol] = acc[i][j][r] + bv;
            }
        }
    }
#undef STAGE
#undef RDA
#undef RDB
#undef MFMA16
#undef PH_MID
#undef PH_END
#undef VM6
#undef VM0
#undef VMNOP
#undef KTILE
}

// ---------- per-row q/k norms + kv partials (NO atomics) ----------
// 4 waves/block, each wave owns 8 rows and a private LDS slice; block writes
// one 1024-float partial to `part`. A tiny reduce kernel sums 128 partials
// per batch. Removes 524K device-scope atomicAdds into a 16 KB region.
__global__ __launch_bounds__(256) void norm_kv(const unsigned short* __restrict__ qkv,
                                               float* __restrict__ rnq,
                                               float* __restrict__ part) {
    __shared__ float kvbuf[4][1024];   // 16 KB, one slice per wave
    const int tid = threadIdx.x, lane = tid & 63, wv = tid >> 6;

    const int row0 = blockIdx.x * 32 + wv * 8;
    float a[4][4] = {};

    for (int rr = 0; rr < 8; rr++) {
        const size_t base = (size_t)(row0 + rr) * 3072;
        float q2 = 0.f;
        #pragma unroll
        for (int c = 0; c < 4; c++) {
            ushort4 qu = *(const ushort4*)&qkv[base + c * 256 + lane * 4];
            float x0 = bf2f(qu.x), x1 = bf2f(qu.y), x2 = bf2f(qu.z), x3 = bf2f(qu.w);
            q2 += x0 * x0 + x1 * x1 + x2 * x2 + x3 * x3;
        }
        #pragma unroll
        for (int m = 32; m; m >>= 1) q2 += __shfl_xor(q2, m, 64);
        if (lane == 0) rnq[row0 + rr] = rsqrtf(q2);

        float k2 = 0.f;
        float kf[4][4];
        #pragma unroll
        for (int c = 0; c < 4; c++) {
            ushort4 ku = *(const ushort4*)&qkv[base + 1024 + c * 256 + lane * 4];
            kf[c][0] = bf2f(ku.x); kf[c][1] = bf2f(ku.y);
            kf[c][2] = bf2f(ku.z); kf[c][3] = bf2f(ku.w);
            k2 += kf[c][0]*kf[c][0] + kf[c][1]*kf[c][1] + kf[c][2]*kf[c][2] + kf[c][3]*kf[c][3];
        }
        #pragma unroll
        for (int m = 32; m; m >>= 1) k2 += __shfl_xor(k2, m, 64);
        const float rk = rsqrtf(k2);

        #pragma unroll
        for (int c = 0; c < 4; c++) {
            ushort4 vu = *(const ushort4*)&qkv[base + 2048 + c * 256 + lane * 4];
            a[c][0] += kf[c][0] * rk * bf2f(vu.x);
            a[c][1] += kf[c][1] * rk * bf2f(vu.y);
            a[c][2] += kf[c][2] * rk * bf2f(vu.z);
            a[c][3] += kf[c][3] * rk * bf2f(vu.w);
        }
    }
    // plain stores into this wave's private slice (full 1024 coverage per wave)
    #pragma unroll
    for (int c = 0; c < 4; c++)
        *(float4*)&kvbuf[wv][c * 256 + lane * 4] = make_float4(a[c][0], a[c][1], a[c][2], a[c][3]);
    __syncthreads();
    float4 s = *(const float4*)&kvbuf[0][tid * 4];
    #pragma unroll
    for (int w = 1; w < 4; w++) {
        float4 t = *(const float4*)&kvbuf[w][tid * 4];
        s.x += t.x; s.y += t.y; s.z += t.z; s.w += t.w;
    }
    *(float4*)&part[(size_t)blockIdx.x * 1024 + tid * 4] = s;
}

// ---------- reduce 128 partials per batch -> kv[4][1024] ----------
__global__ __launch_bounds__(256) void reduce_kv(const float* __restrict__ part,
                                                 float* __restrict__ kv) {
    const int b = blockIdx.x >> 2;
    const int d = (blockIdx.x & 3) * 256 + threadIdx.x;
    float s = 0.f;
    #pragma unroll 8
    for (int j = 0; j < 128; j++)
        s += part[(size_t)(b * 128 + j) * 1024 + d];
    kv[b * 1024 + d] = s;
}

// ---------- out = q_hat * kv  (written into qkv's dead v-region, bf16) ----------
__global__ __launch_bounds__(256) void scale_q(unsigned short* __restrict__ qkv,
                                               const float* __restrict__ rnq,
                                               const float* __restrict__ kv, int T) {
    const int t = blockIdx.x;
    const int b = t / T;
    const int d = threadIdx.x * 4;
    const float rq = rnq[t];
    const size_t base = (size_t)t * 3072;
    ushort4 qu = *(const ushort4*)&qkv[base + d];
    float4 kvv = *(const float4*)&kv[b * 1024 + d];
    ushort4 o;
    o.x = f2bf(bf2f(qu.x) * rq * kvv.x);
    o.y = f2bf(bf2f(qu.y) * rq * kvv.y);
    o.z = f2bf(bf2f(qu.z) * rq * kvv.z);
    o.w = f2bf(bf2f(qu.w) * rq * kvv.w);
    *(ushort4*)&qkv[base + 2048 + d] = o;
}

extern "C" void kernel_launch(void* const* d_in, const int* in_sizes, int n_in,
                              void* d_out, int out_size, void* d_ws, size_t ws_size,
                              hipStream_t stream) {
    const float* x    = (const float*)d_in[0];   // (4,4096,1024)
    const float* Wqkv = (const float*)d_in[1];   // (1024,3072)
    const float* bqkv = (const float*)d_in[2];   // (3072)
    const float* Wout = (const float*)d_in[3];   // (1024,1024)
    const float* bout = (const float*)d_in[4];   // (1024)
    float* out = (float*)d_out;                  // (4,4096,1024) fp32

    // workspace layout (~136 MB)
    char* ws = (char*)d_ws;
    unsigned short* x_bf  = (unsigned short*)(ws + 0);           // 32 MB (dead after GEMM1)
    unsigned short* WqkvT = (unsigned short*)(ws + 33554432);    // 6 MB
    unsigned short* WoutT = (unsigned short*)(ws + 39845888);    // 2 MB
    unsigned short* qkv   = (unsigned short*)(ws + 41943040);    // 96 MB
    float* rnq            = (float*)(ws + 142606336);            // 64 KB
    float* kv             = (float*)(ws + 142671872);            // 16 KB
    float* part           = (float*)(ws + 0);                    // 2 MB, reuses x_bf region

    conv_f32_bf16<<<16384, 256, 0, stream>>>(x, x_bf, 16777216);
    transpose_to_bf16<<<dim3(96, 32), 256, 0, stream>>>(Wqkv, WqkvT, 1024, 3072);
    transpose_to_bf16<<<dim3(32, 32), 256, 0, stream>>>(Wout, WoutT, 1024, 1024);

    // qkv = x @ Wqkv + bqkv   (M=16384, N=3072, K=1024) -> bf16; 64x12 = 768 tiles
    gemm_bf16<true><<<768, 512, 0, stream>>>(x_bf, 1024, WqkvT, 1024, bqkv,
                                             (void*)qkv, 3072, 1024, 12);

    norm_kv<<<512, 256, 0, stream>>>(qkv, rnq, part);
    reduce_kv<<<16, 256, 0, stream>>>(part, kv);

    scale_q<<<16384, 256, 0, stream>>>(qkv, rnq, kv, 4096);

    // y = out @ Wout + bout   (M=16384, N=1024, K=1024) -> fp32 d_out; 64x4 = 256 tiles
    gemm_bf16<false><<<256, 512, 0, stream>>>(qkv + 2048, 3072, WoutT, 1024, bout,
                                              (void*)out, 1024, 1024, 4);
}

// Round 4
// 324.232 us; speedup vs baseline: 1.1726x; 1.0251x over previous
//
#include <hip/hip_runtime.h>

// ---------- types / helpers ----------
typedef __attribute__((ext_vector_type(8))) short short8;   // 8 bf16 = 4 VGPRs
typedef __attribute__((ext_vector_type(4))) float f32x4;

__device__ __forceinline__ float bf2f(unsigned short u) {
    union { unsigned int i; float f; } x; x.i = ((unsigned int)u) << 16; return x.f;
}
__device__ __forceinline__ unsigned short f2bf(float f) {
    union { float f; unsigned int i; } x; x.f = f;
    unsigned int r = x.i + 0x7fffu + ((x.i >> 16) & 1u);   // RTNE
    return (unsigned short)(r >> 16);
}
__device__ __forceinline__ void async_copy16(const void* g, void* l) {
    __builtin_amdgcn_global_load_lds(
        (const __attribute__((address_space(1))) void*)g,
        (__attribute__((address_space(3))) void*)l,
        16, 0, 0);
}

// ---------- fp32 -> bf16 convert (x) ----------
__global__ __launch_bounds__(256) void conv_f32_bf16(const float* __restrict__ in,
                                                     unsigned short* __restrict__ out, int n) {
    int i = (blockIdx.x * 256 + threadIdx.x) * 4;
    if (i < n) {
        float4 v = *(const float4*)&in[i];
        ushort4 o;
        o.x = f2bf(v.x); o.y = f2bf(v.y); o.z = f2bf(v.z); o.w = f2bf(v.w);
        *(ushort4*)&out[i] = o;
    }
}

// ---------- transpose + convert: in (R x C fp32) -> out (C x R bf16) ----------
__global__ __launch_bounds__(256) void transpose_to_bf16(const float* __restrict__ in,
                                                         unsigned short* __restrict__ out,
                                                         int R, int C) {
    __shared__ float tile[32][33];
    int bx = blockIdx.x * 32;                      // C index
    int by = blockIdx.y * 32;                      // R index
    int tx = threadIdx.x & 31, ty = threadIdx.x >> 5;
    #pragma unroll
    for (int r = ty; r < 32; r += 8)
        tile[r][tx] = in[(size_t)(by + r) * C + bx + tx];
    __syncthreads();
    #pragma unroll
    for (int r = ty; r < 32; r += 8)
        out[(size_t)(bx + r) * R + by + tx] = f2bf(tile[tx][r]);
}

// ---------- bf16 GEMM: C[M,N] = A[M,K] * Bt[N,K]^T + bias ----------
// 256x256 tile, BK=64, 512 threads (8 waves 2x4), 8-phase/2-K-tile schedule.
// Round-4 change: C-QUADRANT-major phases with fragment reuse (m201-faithful
// {12,4,8,0} ds_read pattern): ph1 loads A rows0-3 + B cols0-1 (both k-halves),
// ph2 loads only B cols2-3 (A reused), ph3 loads only A rows4-7 (B reused),
// ph4 loads NOTHING (pure-MFMA phase; LDS pipe free for staging write-backs).
// Staging remapped: B1(t+1)@ph1, B0(t+2)@ph2, A0(t+2)@ph3, A1(t+2)@ph4;
// vmcnt(6) at ph4 drains exactly B1(t+1). Never vmcnt(0) in the main loop.
template<bool OUT_BF16>
__global__ __launch_bounds__(512, 2) void gemm_bf16(const unsigned short* __restrict__ A, int lda,
                                                    const unsigned short* __restrict__ Bt, int ldb,
                                                    const float* __restrict__ bias,
                                                    void* __restrict__ C, int ldc, int K, int ntn) {
    __shared__ short smem[65536];   // 128 KiB

    const int tid  = threadIdx.x;
    const int lane = tid & 63;
    const int quad = lane >> 4;
    const int l16  = lane & 15;
    const int wid  = tid >> 6;
    const int wm   = wid >> 2;       // 0..1
    const int wn   = wid & 3;        // 0..3

    // XCD-aware bijective blockIdx swizzle (grids are % 8 == 0)
    const int nwg = gridDim.x;
    const int bid = blockIdx.x;
    const int wg  = (bid & 7) * (nwg >> 3) + (bid >> 3);
    const int m0  = (wg / ntn) * 256;
    const int n0  = (wg % ntn) * 256;

    const int NT = K >> 6;           // K-tiles (16 for K=1024); must be even >= 4

    // ---- hoisted LDS read bases (shorts). Swizzle chunk SW = quad ^ ((l16>>1)&3).
    const int SW8  = (quad ^ ((l16 >> 1) & 3)) * 8;
    const int offA = (wm * 128 + l16) * 32 + SW8;
    const int offB = 16384 + (wn * 64 + l16) * 32 + SW8;
    const short* pA0 = smem + offA;
    const short* pA1 = smem + 32768 + offA;
    const short* pB0 = smem + offB;
    const short* pB1 = smem + 32768 + offB;

    // ---- staging source pointers (advance by 64 shorts per K-tile, 128 per pair)
    // LDS chunk L = j*512+tid -> (r=L>>2, c=L&3), source k-chunk cs = c ^ ((r>>1)&3)
    const unsigned short *aS0, *aS1, *bS0, *bS1;
    {
        const int L0  = tid,        r0 = L0 >> 2, c0 = (L0 & 3) ^ ((r0 >> 1) & 3);
        const int L1  = 512 + tid,  r1 = L1 >> 2, c1 = (L1 & 3) ^ ((r1 >> 1) & 3);
        aS0 = A  + (size_t)(m0 + r0) * lda + c0 * 8;
        aS1 = A  + (size_t)(m0 + r1) * lda + c1 * 8;
        bS0 = Bt + (size_t)(n0 + r0) * ldb + c0 * 8;
        bS1 = Bt + (size_t)(n0 + r1) * ldb + c1 * 8;
    }
    const int dstoff = tid * 8;      // shorts (lane x 16B, linear gload_lds dest)

#define STAGE(BUF, ISB, H, AH) do { \
        short* d_ = smem + (BUF) * 32768 + (ISB) * 16384 + (H) * 8192 + dstoff; \
        async_copy16(((ISB) ? bS0 : aS0) + (AH) * 64 + (H) * 32, d_); \
        async_copy16(((ISB) ? bS1 : aS1) + (AH) * 64 + (H) * 32, d_ + 4096); \
    } while (0)

// A fragment rows IB..IB+3 from k-half H of buffer P (4 x ds_read_b128)
#define RDA4(dst, P, H, IB) do { \
        dst[0] = *(const short8*)(pA##P + ((IB) + 0) * 512 + (H) * 8192); \
        dst[1] = *(const short8*)(pA##P + ((IB) + 1) * 512 + (H) * 8192); \
        dst[2] = *(const short8*)(pA##P + ((IB) + 2) * 512 + (H) * 8192); \
        dst[3] = *(const short8*)(pA##P + ((IB) + 3) * 512 + (H) * 8192); \
    } while (0)
// B fragment cols JB..JB+1 from k-half H of buffer P (2 x ds_read_b128)
#define RDB2(dst, P, H, JB) do { \
        dst[0] = *(const short8*)(pB##P + ((JB) + 0) * 512 + (H) * 8192); \
        dst[1] = *(const short8*)(pB##P + ((JB) + 1) * 512 + (H) * 8192); \
    } while (0)

// One C-quadrant: acc[IB..IB+3][JB..JB+1] over both k-halves (16 MFMA).
// kk-outer order: 8 independent MFMAs, then 8 dependent (2-chains).
#define MFMA_Q(IB, JB, ak0, ak1, bk0, bk1) do { \
        _Pragma("unroll") \
        for (int i_ = 0; i_ < 4; i_++) \
            _Pragma("unroll") \
            for (int j_ = 0; j_ < 2; j_++) \
                acc[(IB) + i_][(JB) + j_] = __builtin_amdgcn_mfma_f32_16x16x32_bf16(ak0[i_], bk0[j_], acc[(IB) + i_][(JB) + j_], 0, 0, 0); \
        _Pragma("unroll") \
        for (int i_ = 0; i_ < 4; i_++) \
            _Pragma("unroll") \
            for (int j_ = 0; j_ < 2; j_++) \
                acc[(IB) + i_][(JB) + j_] = __builtin_amdgcn_mfma_f32_16x16x32_bf16(ak1[i_], bk1[j_], acc[(IB) + i_][(JB) + j_], 0, 0, 0); \
    } while (0)

// barrier-only mid (R3-proven); compiler emits stepped per-operand lgkmcnt.
#define PH_MID() do { \
        __builtin_amdgcn_s_barrier(); \
        __builtin_amdgcn_s_setprio(1); \
    } while (0)
#define PH_END() do { \
        __builtin_amdgcn_s_setprio(0); \
        __builtin_amdgcn_s_barrier(); \
    } while (0)

#define VM6   asm volatile("s_waitcnt vmcnt(6)" ::: "memory")
#define VM0   asm volatile("s_waitcnt vmcnt(0)" ::: "memory")
#define VMNOP ((void)0)

// One K-tile = 4 quadrant phases. P = buffer parity (literal), AH = source
// tile offset, T1 = stage B1(t+1), T2 = stage t+2 pieces.
#define KTILE(P, AH, T1, T2, VMW) do { \
        short8 a0k0[4], a0k1[4], a1k0[4], a1k1[4]; \
        short8 b0k0[2], b0k1[2], b1k0[2], b1k1[2]; \
        /* ph1: A rows0-3 (kk0+kk1) + B cols0-1 (kk0+kk1) = 12 reads; stage B1(t+1) */ \
        RDA4(a0k0, P, 0, 0); RDA4(a0k1, P, 1, 0); \
        RDB2(b0k0, P, 0, 0); RDB2(b0k1, P, 1, 0); \
        if (T1) STAGE((P) ^ 1, 1, 1, (AH) + 1); \
        PH_MID(); MFMA_Q(0, 0, a0k0, a0k1, b0k0, b0k1); PH_END(); \
        /* ph2: B cols2-3 (kk0+kk1) = 4 reads (A reused); stage B0(t+2) */ \
        RDB2(b1k0, P, 0, 2); RDB2(b1k1, P, 1, 2); \
        if (T2) STAGE(P, 1, 0, (AH) + 2); \
        PH_MID(); MFMA_Q(0, 2, a0k0, a0k1, b1k0, b1k1); PH_END(); \
        /* ph3: A rows4-7 (kk0+kk1) = 8 reads (B reused); stage A0(t+2) */ \
        RDA4(a1k0, P, 0, 4); RDA4(a1k1, P, 1, 4); \
        if (T2) STAGE(P, 0, 0, (AH) + 2); \
        PH_MID(); MFMA_Q(4, 2, a1k0, a1k1, b1k0, b1k1); PH_END(); \
        /* ph4: ZERO reads (all reused); stage A1(t+2); counted vmcnt */ \
        if (T2) STAGE(P, 0, 1, (AH) + 2); \
        VMW; \
        PH_MID(); MFMA_Q(4, 0, a1k0, a1k1, b0k0, b0k1); PH_END(); \
    } while (0)

    f32x4 acc[8][4] = {};

    // ---- prologue: tile0 {A0,B0,A1,B1}; tile1 {B0,A0,A1} (B1(1) issued in ph1 of t=0)
    STAGE(0, 0, 0, 0); STAGE(0, 1, 0, 0); STAGE(0, 0, 1, 0); STAGE(0, 1, 1, 0);
    asm volatile("s_waitcnt vmcnt(4)" ::: "memory");
    STAGE(1, 1, 0, 1); STAGE(1, 0, 0, 1); STAGE(1, 0, 1, 1);
    asm volatile("s_waitcnt vmcnt(6)" ::: "memory");   // tile0 fully landed, 3 halves in flight
    __builtin_amdgcn_s_barrier();

    // ---- main loop: pairs of K-tiles (8 phases), tiles 0..NT-3
    for (int u = 0; u + 3 < NT; u += 2) {
        KTILE(0, 0, 1, 1, VM6);
        KTILE(1, 1, 1, 1, VM6);
        aS0 += 128; aS1 += 128; bS0 += 128; bS1 += 128;
    }
    // ---- tail: tile NT-2 (stage B1(NT-1) only, full drain), tile NT-1 (pure compute)
    KTILE(0, 0, 1, 0, VM0);
    KTILE(1, 1, 0, 0, VMNOP);

    // ---- epilogue. C/D layout: col = lane&15, row = quad*4 + r  [m89/m91]
    if (OUT_BF16) {
        __syncthreads();                               // full drain; reuse smem
        unsigned short* tile = (unsigned short*)smem;  // [128][264] padded
        unsigned short* Cp   = (unsigned short*)C;
        #pragma unroll
        for (int hm = 0; hm < 2; hm++) {
            if (wm == hm) {
                #pragma unroll
                for (int j = 0; j < 4; j++) {
                    const int tcol = wn * 64 + j * 16 + l16;
                    const float bv = bias[n0 + tcol];
                    #pragma unroll
                    for (int i = 0; i < 8; i++) {
                        const int trow = i * 16 + quad * 4;
                        #pragma unroll
                        for (int r = 0; r < 4; r++)
                            tile[(trow + r) * 264 + tcol] = f2bf(acc[i][j][r] + bv);
                    }
                }
            }
            __syncthreads();
            #pragma unroll
            for (int pp = 0; pp < 8; pp++) {
                const int row = pp * 16 + (tid >> 5);
                const int ch  = tid & 31;
                short8 v = *(const short8*)&tile[row * 264 + ch * 8];
                *(short8*)&Cp[(size_t)(m0 + hm * 128 + row) * ldc + n0 + ch * 8] = v;
            }
            __syncthreads();
        }
    } else {
        float* Cp = (float*)C;
        #pragma unroll
        for (int j = 0; j < 4; j++) {
            const int gcol = n0 + wn * 64 + j * 16 + l16;
            const float bv = bias[gcol];
            #pragma unroll
            for (int i = 0; i < 8; i++) {
                const int grow = m0 + wm * 128 + i * 16 + quad * 4;
                #pragma unroll
                for (int r = 0; r < 4; r++)
                    Cp[(size_t)(grow + r) * ldc + gcol] = acc[i][j][r] + bv;
            }
        }
    }
#undef STAGE
#undef RDA4
#undef RDB2
#undef MFMA_Q
#undef PH_MID
#undef PH_END
#undef VM6
#undef VM0
#undef VMNOP
#undef KTILE
}

// ---------- per-row q/k norms + kv partials (NO atomics) ----------
// 4 waves/block, each wave owns 8 rows and a private LDS slice; block writes
// one 1024-float partial to `part`. A tiny reduce kernel sums 128 partials
// per batch. Removes 524K device-scope atomicAdds into a 16 KB region.
__global__ __launch_bounds__(256) void norm_kv(const unsigned short* __restrict__ qkv,
                                               float* __restrict__ rnq,
                                               float* __restrict__ part) {
    __shared__ float kvbuf[4][1024];   // 16 KB, one slice per wave
    const int tid = threadIdx.x, lane = tid & 63, wv = tid >> 6;

    const int row0 = blockIdx.x * 32 + wv * 8;
    float a[4][4] = {};

    for (int rr = 0; rr < 8; rr++) {
        const size_t base = (size_t)(row0 + rr) * 3072;
        float q2 = 0.f;
        #pragma unroll
        for (int c = 0; c < 4; c++) {
            ushort4 qu = *(const ushort4*)&qkv[base + c * 256 + lane * 4];
            float x0 = bf2f(qu.x), x1 = bf2f(qu.y), x2 = bf2f(qu.z), x3 = bf2f(qu.w);
            q2 += x0 * x0 + x1 * x1 + x2 * x2 + x3 * x3;
        }
        #pragma unroll
        for (int m = 32; m; m >>= 1) q2 += __shfl_xor(q2, m, 64);
        if (lane == 0) rnq[row0 + rr] = rsqrtf(q2);

        float k2 = 0.f;
        float kf[4][4];
        #pragma unroll
        for (int c = 0; c < 4; c++) {
            ushort4 ku = *(const ushort4*)&qkv[base + 1024 + c * 256 + lane * 4];
            kf[c][0] = bf2f(ku.x); kf[c][1] = bf2f(ku.y);
            kf[c][2] = bf2f(ku.z); kf[c][3] = bf2f(ku.w);
            k2 += kf[c][0]*kf[c][0] + kf[c][1]*kf[c][1] + kf[c][2]*kf[c][2] + kf[c][3]*kf[c][3];
        }
        #pragma unroll
        for (int m = 32; m; m >>= 1) k2 += __shfl_xor(k2, m, 64);
        const float rk = rsqrtf(k2);

        #pragma unroll
        for (int c = 0; c < 4; c++) {
            ushort4 vu = *(const ushort4*)&qkv[base + 2048 + c * 256 + lane * 4];
            a[c][0] += kf[c][0] * rk * bf2f(vu.x);
            a[c][1] += kf[c][1] * rk * bf2f(vu.y);
            a[c][2] += kf[c][2] * rk * bf2f(vu.z);
            a[c][3] += kf[c][3] * rk * bf2f(vu.w);
        }
    }
    // plain stores into this wave's private slice (full 1024 coverage per wave)
    #pragma unroll
    for (int c = 0; c < 4; c++)
        *(float4*)&kvbuf[wv][c * 256 + lane * 4] = make_float4(a[c][0], a[c][1], a[c][2], a[c][3]);
    __syncthreads();
    float4 s = *(const float4*)&kvbuf[0][tid * 4];
    #pragma unroll
    for (int w = 1; w < 4; w++) {
        float4 t = *(const float4*)&kvbuf[w][tid * 4];
        s.x += t.x; s.y += t.y; s.z += t.z; s.w += t.w;
    }
    *(float4*)&part[(size_t)blockIdx.x * 1024 + tid * 4] = s;
}

// ---------- reduce 128 partials per batch -> kv[4][1024] ----------
__global__ __launch_bounds__(256) void reduce_kv(const float* __restrict__ part,
                                                 float* __restrict__ kv) {
    const int b = blockIdx.x >> 2;
    const int d = (blockIdx.x & 3) * 256 + threadIdx.x;
    float s = 0.f;
    #pragma unroll 8
    for (int j = 0; j < 128; j++)
        s += part[(size_t)(b * 128 + j) * 1024 + d];
    kv[b * 1024 + d] = s;
}

// ---------- out = q_hat * kv  (written into qkv's dead v-region, bf16) ----------
__global__ __launch_bounds__(256) void scale_q(unsigned short* __restrict__ qkv,
                                               const float* __restrict__ rnq,
                                               const float* __restrict__ kv, int T) {
    const int t = blockIdx.x;
    const int b = t / T;
    const int d = threadIdx.x * 4;
    const float rq = rnq[t];
    const size_t base = (size_t)t * 3072;
    ushort4 qu = *(const ushort4*)&qkv[base + d];
    float4 kvv = *(const float4*)&kv[b * 1024 + d];
    ushort4 o;
    o.x = f2bf(bf2f(qu.x) * rq * kvv.x);
    o.y = f2bf(bf2f(qu.y) * rq * kvv.y);
    o.z = f2bf(bf2f(qu.z) * rq * kvv.z);
    o.w = f2bf(bf2f(qu.w) * rq * kvv.w);
    *(ushort4*)&qkv[base + 2048 + d] = o;
}

extern "C" void kernel_launch(void* const* d_in, const int* in_sizes, int n_in,
                              void* d_out, int out_size, void* d_ws, size_t ws_size,
                              hipStream_t stream) {
    const float* x    = (const float*)d_in[0];   // (4,4096,1024)
    const float* Wqkv = (const float*)d_in[1];   // (1024,3072)
    const float* bqkv = (const float*)d_in[2];   // (3072)
    const float* Wout = (const float*)d_in[3];   // (1024,1024)
    const float* bout = (const float*)d_in[4];   // (1024)
    float* out = (float*)d_out;                  // (4,4096,1024) fp32

    // workspace layout (~136 MB)
    char* ws = (char*)d_ws;
    unsigned short* x_bf  = (unsigned short*)(ws + 0);           // 32 MB (dead after GEMM1)
    unsigned short* WqkvT = (unsigned short*)(ws + 33554432);    // 6 MB
    unsigned short* WoutT = (unsigned short*)(ws + 39845888);    // 2 MB
    unsigned short* qkv   = (unsigned short*)(ws + 41943040);    // 96 MB
    float* rnq            = (float*)(ws + 142606336);            // 64 KB
    float* kv             = (float*)(ws + 142671872);            // 16 KB
    float* part           = (float*)(ws + 0);                    // 2 MB, reuses x_bf region

    conv_f32_bf16<<<16384, 256, 0, stream>>>(x, x_bf, 16777216);
    transpose_to_bf16<<<dim3(96, 32), 256, 0, stream>>>(Wqkv, WqkvT, 1024, 3072);
    transpose_to_bf16<<<dim3(32, 32), 256, 0, stream>>>(Wout, WoutT, 1024, 1024);

    // qkv = x @ Wqkv + bqkv   (M=16384, N=3072, K=1024) -> bf16; 64x12 = 768 tiles
    gemm_bf16<true><<<768, 512, 0, stream>>>(x_bf, 1024, WqkvT, 1024, bqkv,
                                             (void*)qkv, 3072, 1024, 12);

    norm_kv<<<512, 256, 0, stream>>>(qkv, rnq, part);
    reduce_kv<<<16, 256, 0, stream>>>(part, kv);

    scale_q<<<16384, 256, 0, stream>>>(qkv, rnq, kv, 4096);

    // y = out @ Wout + bout   (M=16384, N=1024, K=1024) -> fp32 d_out; 64x4 = 256 tiles
    gemm_bf16<false><<<256, 512, 0, stream>>>(qkv + 2048, 3072, WoutT, 1024, bout,
                                              (void*)out, 1024, 1024, 4);
}

// Round 5
// 318.204 us; speedup vs baseline: 1.1948x; 1.0189x over previous
//
#include <hip/hip_runtime.h>

// ---------- types / helpers ----------
typedef __attribute__((ext_vector_type(8))) short short8;   // 8 bf16 = 4 VGPRs
typedef __attribute__((ext_vector_type(4))) float f32x4;

__device__ __forceinline__ float bf2f(unsigned short u) {
    union { unsigned int i; float f; } x; x.i = ((unsigned int)u) << 16; return x.f;
}
__device__ __forceinline__ unsigned short f2bf(float f) {
    union { float f; unsigned int i; } x; x.f = f;
    unsigned int r = x.i + 0x7fffu + ((x.i >> 16) & 1u);   // RTNE
    return (unsigned short)(r >> 16);
}
__device__ __forceinline__ void async_copy16(const void* g, void* l) {
    __builtin_amdgcn_global_load_lds(
        (const __attribute__((address_space(1))) void*)g,
        (__attribute__((address_space(3))) void*)l,
        16, 0, 0);
}

// ---------- fused prep: x fp32->bf16 (blocks 0..8191), Wqkv^T (8192..11263),
// ---------- Wout^T (11264..12287). Saves two kernel launches.
__global__ __launch_bounds__(256) void prep(const float* __restrict__ x,
                                            const float* __restrict__ Wqkv,
                                            const float* __restrict__ Wout,
                                            unsigned short* __restrict__ x_bf,
                                            unsigned short* __restrict__ WqkvT,
                                            unsigned short* __restrict__ WoutT) {
    __shared__ float tile[32][33];
    const int blk = blockIdx.x;
    if (blk < 8192) {
        // convert 16,777,216 floats, 8 per thread (2x float4 in, 1x short8 out)
        const size_t i = ((size_t)blk * 256 + threadIdx.x) * 8;
        float4 v0 = *(const float4*)&x[i];
        float4 v1 = *(const float4*)&x[i + 4];
        short8 o;
        o[0] = (short)f2bf(v0.x); o[1] = (short)f2bf(v0.y);
        o[2] = (short)f2bf(v0.z); o[3] = (short)f2bf(v0.w);
        o[4] = (short)f2bf(v1.x); o[5] = (short)f2bf(v1.y);
        o[6] = (short)f2bf(v1.z); o[7] = (short)f2bf(v1.w);
        *(short8*)&x_bf[i] = o;
        return;
    }
    // transpose + convert: in (R x C fp32) -> out (C x R bf16), 32x32 tiles
    const float* in;
    unsigned short* out;
    int R, C, idx;
    if (blk < 11264) { in = Wqkv; out = WqkvT; R = 1024; C = 3072; idx = blk - 8192; }
    else             { in = Wout; out = WoutT; R = 1024; C = 1024; idx = blk - 11264; }
    const int nbx = C / 32;
    const int bx = (idx % nbx) * 32;
    const int by = (idx / nbx) * 32;
    const int tx = threadIdx.x & 31, ty = threadIdx.x >> 5;
    #pragma unroll
    for (int r = ty; r < 32; r += 8)
        tile[r][tx] = in[(size_t)(by + r) * C + bx + tx];
    __syncthreads();
    #pragma unroll
    for (int r = ty; r < 32; r += 8)
        out[(size_t)(bx + r) * R + by + tx] = f2bf(tile[tx][r]);
}

// ---------- bf16 GEMM: C[M,N] = A[M,K] * Bt[N,K]^T + bias ----------
// 256x256 tile, BK=64, 512 threads (8 waves 2x4), 8-phase/2-K-tile schedule.
// (R4 schedule, unchanged: C-quadrant-major phases {12,4,8,0} ds_reads,
// staging B1(t+1)@ph1, B0(t+2)@ph2, A0(t+2)@ph3, A1(t+2)@ph4, vmcnt(6)@ph4.)
template<bool OUT_BF16>
__global__ __launch_bounds__(512, 2) void gemm_bf16(const unsigned short* __restrict__ A, int lda,
                                                    const unsigned short* __restrict__ Bt, int ldb,
                                                    const float* __restrict__ bias,
                                                    void* __restrict__ C, int ldc, int K, int ntn) {
    __shared__ short smem[65536];   // 128 KiB

    const int tid  = threadIdx.x;
    const int lane = tid & 63;
    const int quad = lane >> 4;
    const int l16  = lane & 15;
    const int wid  = tid >> 6;
    const int wm   = wid >> 2;       // 0..1
    const int wn   = wid & 3;        // 0..3

    // XCD-aware bijective blockIdx swizzle (grids are % 8 == 0)
    const int nwg = gridDim.x;
    const int bid = blockIdx.x;
    const int wg  = (bid & 7) * (nwg >> 3) + (bid >> 3);
    const int m0  = (wg / ntn) * 256;
    const int n0  = (wg % ntn) * 256;

    const int NT = K >> 6;           // K-tiles (16 for K=1024); must be even >= 4

    // ---- hoisted LDS read bases (shorts). Swizzle chunk SW = quad ^ ((l16>>1)&3).
    const int SW8  = (quad ^ ((l16 >> 1) & 3)) * 8;
    const int offA = (wm * 128 + l16) * 32 + SW8;
    const int offB = 16384 + (wn * 64 + l16) * 32 + SW8;
    const short* pA0 = smem + offA;
    const short* pA1 = smem + 32768 + offA;
    const short* pB0 = smem + offB;
    const short* pB1 = smem + 32768 + offB;

    // ---- staging source pointers (advance by 64 shorts per K-tile, 128 per pair)
    // LDS chunk L = j*512+tid -> (r=L>>2, c=L&3), source k-chunk cs = c ^ ((r>>1)&3)
    const unsigned short *aS0, *aS1, *bS0, *bS1;
    {
        const int L0  = tid,        r0 = L0 >> 2, c0 = (L0 & 3) ^ ((r0 >> 1) & 3);
        const int L1  = 512 + tid,  r1 = L1 >> 2, c1 = (L1 & 3) ^ ((r1 >> 1) & 3);
        aS0 = A  + (size_t)(m0 + r0) * lda + c0 * 8;
        aS1 = A  + (size_t)(m0 + r1) * lda + c1 * 8;
        bS0 = Bt + (size_t)(n0 + r0) * ldb + c0 * 8;
        bS1 = Bt + (size_t)(n0 + r1) * ldb + c1 * 8;
    }
    const int dstoff = tid * 8;      // shorts (lane x 16B, linear gload_lds dest)

#define STAGE(BUF, ISB, H, AH) do { \
        short* d_ = smem + (BUF) * 32768 + (ISB) * 16384 + (H) * 8192 + dstoff; \
        async_copy16(((ISB) ? bS0 : aS0) + (AH) * 64 + (H) * 32, d_); \
        async_copy16(((ISB) ? bS1 : aS1) + (AH) * 64 + (H) * 32, d_ + 4096); \
    } while (0)

// A fragment rows IB..IB+3 from k-half H of buffer P (4 x ds_read_b128)
#define RDA4(dst, P, H, IB) do { \
        dst[0] = *(const short8*)(pA##P + ((IB) + 0) * 512 + (H) * 8192); \
        dst[1] = *(const short8*)(pA##P + ((IB) + 1) * 512 + (H) * 8192); \
        dst[2] = *(const short8*)(pA##P + ((IB) + 2) * 512 + (H) * 8192); \
        dst[3] = *(const short8*)(pA##P + ((IB) + 3) * 512 + (H) * 8192); \
    } while (0)
// B fragment cols JB..JB+1 from k-half H of buffer P (2 x ds_read_b128)
#define RDB2(dst, P, H, JB) do { \
        dst[0] = *(const short8*)(pB##P + ((JB) + 0) * 512 + (H) * 8192); \
        dst[1] = *(const short8*)(pB##P + ((JB) + 1) * 512 + (H) * 8192); \
    } while (0)

// One C-quadrant: acc[IB..IB+3][JB..JB+1] over both k-halves (16 MFMA).
#define MFMA_Q(IB, JB, ak0, ak1, bk0, bk1) do { \
        _Pragma("unroll") \
        for (int i_ = 0; i_ < 4; i_++) \
            _Pragma("unroll") \
            for (int j_ = 0; j_ < 2; j_++) \
                acc[(IB) + i_][(JB) + j_] = __builtin_amdgcn_mfma_f32_16x16x32_bf16(ak0[i_], bk0[j_], acc[(IB) + i_][(JB) + j_], 0, 0, 0); \
        _Pragma("unroll") \
        for (int i_ = 0; i_ < 4; i_++) \
            _Pragma("unroll") \
            for (int j_ = 0; j_ < 2; j_++) \
                acc[(IB) + i_][(JB) + j_] = __builtin_amdgcn_mfma_f32_16x16x32_bf16(ak1[i_], bk1[j_], acc[(IB) + i_][(JB) + j_], 0, 0, 0); \
    } while (0)

#define PH_MID() do { \
        __builtin_amdgcn_s_barrier(); \
        __builtin_amdgcn_s_setprio(1); \
    } while (0)
#define PH_END() do { \
        __builtin_amdgcn_s_setprio(0); \
        __builtin_amdgcn_s_barrier(); \
    } while (0)

#define VM6   asm volatile("s_waitcnt vmcnt(6)" ::: "memory")
#define VM0   asm volatile("s_waitcnt vmcnt(0)" ::: "memory")
#define VMNOP ((void)0)

#define KTILE(P, AH, T1, T2, VMW) do { \
        short8 a0k0[4], a0k1[4], a1k0[4], a1k1[4]; \
        short8 b0k0[2], b0k1[2], b1k0[2], b1k1[2]; \
        /* ph1: A rows0-3 (kk0+kk1) + B cols0-1 (kk0+kk1) = 12 reads; stage B1(t+1) */ \
        RDA4(a0k0, P, 0, 0); RDA4(a0k1, P, 1, 0); \
        RDB2(b0k0, P, 0, 0); RDB2(b0k1, P, 1, 0); \
        if (T1) STAGE((P) ^ 1, 1, 1, (AH) + 1); \
        PH_MID(); MFMA_Q(0, 0, a0k0, a0k1, b0k0, b0k1); PH_END(); \
        /* ph2: B cols2-3 (kk0+kk1) = 4 reads (A reused); stage B0(t+2) */ \
        RDB2(b1k0, P, 0, 2); RDB2(b1k1, P, 1, 2); \
        if (T2) STAGE(P, 1, 0, (AH) + 2); \
        PH_MID(); MFMA_Q(0, 2, a0k0, a0k1, b1k0, b1k1); PH_END(); \
        /* ph3: A rows4-7 (kk0+kk1) = 8 reads (B reused); stage A0(t+2) */ \
        RDA4(a1k0, P, 0, 4); RDA4(a1k1, P, 1, 4); \
        if (T2) STAGE(P, 0, 0, (AH) + 2); \
        PH_MID(); MFMA_Q(4, 2, a1k0, a1k1, b1k0, b1k1); PH_END(); \
        /* ph4: ZERO reads (all reused); stage A1(t+2); counted vmcnt */ \
        if (T2) STAGE(P, 0, 1, (AH) + 2); \
        VMW; \
        PH_MID(); MFMA_Q(4, 0, a1k0, a1k1, b0k0, b0k1); PH_END(); \
    } while (0)

    f32x4 acc[8][4] = {};

    // ---- prologue: tile0 {A0,B0,A1,B1}; tile1 {B0,A0,A1} (B1(1) issued in ph1 of t=0)
    STAGE(0, 0, 0, 0); STAGE(0, 1, 0, 0); STAGE(0, 0, 1, 0); STAGE(0, 1, 1, 0);
    asm volatile("s_waitcnt vmcnt(4)" ::: "memory");
    STAGE(1, 1, 0, 1); STAGE(1, 0, 0, 1); STAGE(1, 0, 1, 1);
    asm volatile("s_waitcnt vmcnt(6)" ::: "memory");   // tile0 fully landed, 3 halves in flight
    __builtin_amdgcn_s_barrier();

    // ---- main loop: pairs of K-tiles (8 phases), tiles 0..NT-3
    for (int u = 0; u + 3 < NT; u += 2) {
        KTILE(0, 0, 1, 1, VM6);
        KTILE(1, 1, 1, 1, VM6);
        aS0 += 128; aS1 += 128; bS0 += 128; bS1 += 128;
    }
    // ---- tail: tile NT-2 (stage B1(NT-1) only, full drain), tile NT-1 (pure compute)
    KTILE(0, 0, 1, 0, VM0);
    KTILE(1, 1, 0, 0, VMNOP);

    // ---- epilogue. C/D layout: col = lane&15, row = quad*4 + r  [m89/m91]
    if (OUT_BF16) {
        __syncthreads();                               // full drain; reuse smem
        unsigned short* tile = (unsigned short*)smem;  // [128][264] padded
        unsigned short* Cp   = (unsigned short*)C;
        #pragma unroll
        for (int hm = 0; hm < 2; hm++) {
            if (wm == hm) {
                #pragma unroll
                for (int j = 0; j < 4; j++) {
                    const int tcol = wn * 64 + j * 16 + l16;
                    const float bv = bias[n0 + tcol];
                    #pragma unroll
                    for (int i = 0; i < 8; i++) {
                        const int trow = i * 16 + quad * 4;
                        #pragma unroll
                        for (int r = 0; r < 4; r++)
                            tile[(trow + r) * 264 + tcol] = f2bf(acc[i][j][r] + bv);
                    }
                }
            }
            __syncthreads();
            #pragma unroll
            for (int pp = 0; pp < 8; pp++) {
                const int row = pp * 16 + (tid >> 5);
                const int ch  = tid & 31;
                short8 v = *(const short8*)&tile[row * 264 + ch * 8];
                *(short8*)&Cp[(size_t)(m0 + hm * 128 + row) * ldc + n0 + ch * 8] = v;
            }
            __syncthreads();
        }
    } else {
        float* Cp = (float*)C;
        #pragma unroll
        for (int j = 0; j < 4; j++) {
            const int gcol = n0 + wn * 64 + j * 16 + l16;
            const float bv = bias[gcol];
            #pragma unroll
            for (int i = 0; i < 8; i++) {
                const int grow = m0 + wm * 128 + i * 16 + quad * 4;
                #pragma unroll
                for (int r = 0; r < 4; r++)
                    Cp[(size_t)(grow + r) * ldc + gcol] = acc[i][j][r] + bv;
            }
        }
    }
#undef STAGE
#undef RDA4
#undef RDB2
#undef MFMA_Q
#undef PH_MID
#undef PH_END
#undef VM6
#undef VM0
#undef VMNOP
#undef KTILE
}

// ---------- per-row q/k norms + kv partials (NO atomics) ----------
// Round-5: 1024 blocks (4/CU, 50% occupancy), 16B short8 loads, 4 rows/wave.
// Block writes one 1024-float partial; reduce_kv sums 256 partials/batch.
__global__ __launch_bounds__(256) void norm_kv(const unsigned short* __restrict__ qkv,
                                               float* __restrict__ rnq,
                                               float* __restrict__ part) {
    __shared__ float kvbuf[4][1024];   // 16 KB, one slice per wave
    const int tid = threadIdx.x, lane = tid & 63, wv = tid >> 6;

    const int row0 = blockIdx.x * 16 + wv * 4;
    float a[2][8] = {};

    #pragma unroll
    for (int rr = 0; rr < 4; rr++) {
        const size_t base = (size_t)(row0 + rr) * 3072;
        float q2 = 0.f;
        #pragma unroll
        for (int c = 0; c < 2; c++) {
            short8 qu = *(const short8*)&qkv[base + c * 512 + lane * 8];
            #pragma unroll
            for (int j = 0; j < 8; j++) {
                float v = bf2f((unsigned short)qu[j]);
                q2 += v * v;
            }
        }
        #pragma unroll
        for (int m = 32; m; m >>= 1) q2 += __shfl_xor(q2, m, 64);
        if (lane == 0) rnq[row0 + rr] = rsqrtf(q2);

        float k2 = 0.f;
        float kf[2][8];
        #pragma unroll
        for (int c = 0; c < 2; c++) {
            short8 ku = *(const short8*)&qkv[base + 1024 + c * 512 + lane * 8];
            #pragma unroll
            for (int j = 0; j < 8; j++) {
                kf[c][j] = bf2f((unsigned short)ku[j]);
                k2 += kf[c][j] * kf[c][j];
            }
        }
        #pragma unroll
        for (int m = 32; m; m >>= 1) k2 += __shfl_xor(k2, m, 64);
        const float rk = rsqrtf(k2);

        #pragma unroll
        for (int c = 0; c < 2; c++) {
            short8 vu = *(const short8*)&qkv[base + 2048 + c * 512 + lane * 8];
            #pragma unroll
            for (int j = 0; j < 8; j++)
                a[c][j] += kf[c][j] * rk * bf2f((unsigned short)vu[j]);
        }
    }
    // plain stores into this wave's private slice (full 1024 coverage per wave)
    #pragma unroll
    for (int c = 0; c < 2; c++) {
        *(float4*)&kvbuf[wv][c * 512 + lane * 8]     = make_float4(a[c][0], a[c][1], a[c][2], a[c][3]);
        *(float4*)&kvbuf[wv][c * 512 + lane * 8 + 4] = make_float4(a[c][4], a[c][5], a[c][6], a[c][7]);
    }
    __syncthreads();
    float4 s = *(const float4*)&kvbuf[0][tid * 4];
    #pragma unroll
    for (int w = 1; w < 4; w++) {
        float4 t = *(const float4*)&kvbuf[w][tid * 4];
        s.x += t.x; s.y += t.y; s.z += t.z; s.w += t.w;
    }
    *(float4*)&part[(size_t)blockIdx.x * 1024 + tid * 4] = s;
}

// ---------- reduce 256 partials per batch -> kv[4][1024] ----------
// 32 blocks: (batch b = bid>>3, 128-col chunk c0 = (bid&7)*128); 256 threads:
// col = c0 + (tid&127), half = tid>>7 sums 128 partial rows; pairwise combine.
__global__ __launch_bounds__(256) void reduce_kv(const float* __restrict__ part,
                                                 float* __restrict__ kv) {
    __shared__ float red[256];
    const int b    = blockIdx.x >> 3;
    const int c0   = (blockIdx.x & 7) * 128;
    const int col  = c0 + (threadIdx.x & 127);
    const int half = threadIdx.x >> 7;
    float s = 0.f;
    #pragma unroll 8
    for (int r = 0; r < 128; r++)
        s += part[(size_t)(b * 256 + half * 128 + r) * 1024 + col];
    red[threadIdx.x] = s;
    __syncthreads();
    if (half == 0)
        kv[b * 1024 + col] = red[threadIdx.x] + red[threadIdx.x + 128];
}

// ---------- out = q_hat * kv  (written into qkv's dead v-region, bf16) ----------
// Round-5: 4096 blocks, 4 rows/block (1 per wave), 16B loads/stores.
__global__ __launch_bounds__(256) void scale_q(unsigned short* __restrict__ qkv,
                                               const float* __restrict__ rnq,
                                               const float* __restrict__ kv) {
    const int lane = threadIdx.x & 63, wv = threadIdx.x >> 6;
    const int t = blockIdx.x * 4 + wv;
    const int b = t >> 12;                 // T = 4096 rows per batch
    const float rq = rnq[t];
    const size_t base = (size_t)t * 3072;
    #pragma unroll
    for (int c = 0; c < 2; c++) {
        const int d = c * 512 + lane * 8;
        short8 qu = *(const short8*)&qkv[base + d];
        float4 k0 = *(const float4*)&kv[b * 1024 + d];
        float4 k1 = *(const float4*)&kv[b * 1024 + d + 4];
        short8 o;
        o[0] = (short)f2bf(bf2f((unsigned short)qu[0]) * rq * k0.x);
        o[1] = (short)f2bf(bf2f((unsigned short)qu[1]) * rq * k0.y);
        o[2] = (short)f2bf(bf2f((unsigned short)qu[2]) * rq * k0.z);
        o[3] = (short)f2bf(bf2f((unsigned short)qu[3]) * rq * k0.w);
        o[4] = (short)f2bf(bf2f((unsigned short)qu[4]) * rq * k1.x);
        o[5] = (short)f2bf(bf2f((unsigned short)qu[5]) * rq * k1.y);
        o[6] = (short)f2bf(bf2f((unsigned short)qu[6]) * rq * k1.z);
        o[7] = (short)f2bf(bf2f((unsigned short)qu[7]) * rq * k1.w);
        *(short8*)&qkv[base + 2048 + d] = o;
    }
}

extern "C" void kernel_launch(void* const* d_in, const int* in_sizes, int n_in,
                              void* d_out, int out_size, void* d_ws, size_t ws_size,
                              hipStream_t stream) {
    const float* x    = (const float*)d_in[0];   // (4,4096,1024)
    const float* Wqkv = (const float*)d_in[1];   // (1024,3072)
    const float* bqkv = (const float*)d_in[2];   // (3072)
    const float* Wout = (const float*)d_in[3];   // (1024,1024)
    const float* bout = (const float*)d_in[4];   // (1024)
    float* out = (float*)d_out;                  // (4,4096,1024) fp32

    // workspace layout (~136 MB)
    char* ws = (char*)d_ws;
    unsigned short* x_bf  = (unsigned short*)(ws + 0);           // 32 MB (dead after GEMM1)
    unsigned short* WqkvT = (unsigned short*)(ws + 33554432);    // 6 MB
    unsigned short* WoutT = (unsigned short*)(ws + 39845888);    // 2 MB
    unsigned short* qkv   = (unsigned short*)(ws + 41943040);    // 96 MB
    float* rnq            = (float*)(ws + 142606336);            // 64 KB
    float* kv             = (float*)(ws + 142671872);            // 16 KB
    float* part           = (float*)(ws + 0);                    // 4 MB, reuses x_bf region

    // fused: x conversion + both weight transposes
    prep<<<12288, 256, 0, stream>>>(x, Wqkv, Wout, x_bf, WqkvT, WoutT);

    // qkv = x @ Wqkv + bqkv   (M=16384, N=3072, K=1024) -> bf16; 64x12 = 768 tiles
    gemm_bf16<true><<<768, 512, 0, stream>>>(x_bf, 1024, WqkvT, 1024, bqkv,
                                             (void*)qkv, 3072, 1024, 12);

    norm_kv<<<1024, 256, 0, stream>>>(qkv, rnq, part);
    reduce_kv<<<32, 256, 0, stream>>>(part, kv);

    scale_q<<<4096, 256, 0, stream>>>(qkv, rnq, kv);

    // y = out @ Wout + bout   (M=16384, N=1024, K=1024) -> fp32 d_out; 64x4 = 256 tiles
    gemm_bf16<false><<<256, 512, 0, stream>>>(qkv + 2048, 3072, WoutT, 1024, bout,
                                              (void*)out, 1024, 1024, 4);
}

// Round 7
// 304.595 us; speedup vs baseline: 1.2481x; 1.0447x over previous
//
#include <hip/hip_runtime.h>

// ---------- types / helpers ----------
typedef __attribute__((ext_vector_type(8))) short short8;   // 8 bf16 = 4 VGPRs
typedef __attribute__((ext_vector_type(4))) float f32x4;

__device__ __forceinline__ float bf2f(unsigned short u) {
    union { unsigned int i; float f; } x; x.i = ((unsigned int)u) << 16; return x.f;
}
__device__ __forceinline__ unsigned short f2bf(float f) {
    union { float f; unsigned int i; } x; x.f = f;
    unsigned int r = x.i + 0x7fffu + ((x.i >> 16) & 1u);   // RTNE
    return (unsigned short)(r >> 16);
}
__device__ __forceinline__ void async_copy16(const void* g, void* l) {
    __builtin_amdgcn_global_load_lds(
        (const __attribute__((address_space(1))) void*)g,
        (__attribute__((address_space(3))) void*)l,
        16, 0, 0);
}

// ---------- fused prep: x fp32->bf16 (blocks 0..8191), Wqkv^T (8192..11263),
// ---------- Wout^T (11264..12287).
__global__ __launch_bounds__(256) void prep(const float* __restrict__ x,
                                            const float* __restrict__ Wqkv,
                                            const float* __restrict__ Wout,
                                            unsigned short* __restrict__ x_bf,
                                            unsigned short* __restrict__ WqkvT,
                                            unsigned short* __restrict__ WoutT) {
    __shared__ float tile[32][33];
    const int blk = blockIdx.x;
    if (blk < 8192) {
        const size_t i = ((size_t)blk * 256 + threadIdx.x) * 8;
        float4 v0 = *(const float4*)&x[i];
        float4 v1 = *(const float4*)&x[i + 4];
        short8 o;
        o[0] = (short)f2bf(v0.x); o[1] = (short)f2bf(v0.y);
        o[2] = (short)f2bf(v0.z); o[3] = (short)f2bf(v0.w);
        o[4] = (short)f2bf(v1.x); o[5] = (short)f2bf(v1.y);
        o[6] = (short)f2bf(v1.z); o[7] = (short)f2bf(v1.w);
        *(short8*)&x_bf[i] = o;
        return;
    }
    const float* in;
    unsigned short* out;
    int R, C, idx;
    if (blk < 11264) { in = Wqkv; out = WqkvT; R = 1024; C = 3072; idx = blk - 8192; }
    else             { in = Wout; out = WoutT; R = 1024; C = 1024; idx = blk - 11264; }
    const int nbx = C / 32;
    const int bx = (idx % nbx) * 32;
    const int by = (idx / nbx) * 32;
    const int tx = threadIdx.x & 31, ty = threadIdx.x >> 5;
    #pragma unroll
    for (int r = ty; r < 32; r += 8)
        tile[r][tx] = in[(size_t)(by + r) * C + bx + tx];
    __syncthreads();
    #pragma unroll
    for (int r = ty; r < 32; r += 8)
        out[(size_t)(bx + r) * R + by + tx] = f2bf(tile[tx][r]);
}

// ---------- bf16 GEMM: C[M,N] = A[M,K] * Bt[N,K]^T + bias ----------
// 256x256 tile, BK=64, 512 threads (8 waves 2x4). K-loop = R4 schedule (FROZEN):
// C-quadrant-major phases {12,4,8,0} ds_reads, staging B1(t+1)@ph1, B0(t+2)@ph2,
// A0(t+2)@ph3, A1(t+2)@ph4, vmcnt(6)@ph4, never vmcnt(0) in the main loop.
// (a) per-batch B panel (bstride): Bt += (m0>>12)*bstride;
// (b) fp32 epilogue restaged through LDS (coalesced 1KiB-segment stores) with
// per-row rq scaling folded in: y = rq[row]*acc + bias.
template<bool OUT_BF16>
__global__ __launch_bounds__(512, 2) void gemm_bf16(const unsigned short* __restrict__ A, int lda,
                                                    const unsigned short* __restrict__ Bt, int ldb,
                                                    const float* __restrict__ bias,
                                                    const float* __restrict__ rq,
                                                    void* __restrict__ C, int ldc, int K, int ntn,
                                                    int bstride) {
    __shared__ short smem[65536];   // 128 KiB

    const int tid  = threadIdx.x;
    const int lane = tid & 63;
    const int quad = lane >> 4;
    const int l16  = lane & 15;
    const int wid  = tid >> 6;
    const int wm   = wid >> 2;       // 0..1
    const int wn   = wid & 3;        // 0..3

    // XCD-aware bijective blockIdx swizzle (grids are % 8 == 0)
    const int nwg = gridDim.x;
    const int bid = blockIdx.x;
    const int wg  = (bid & 7) * (nwg >> 3) + (bid >> 3);
    const int m0  = (wg / ntn) * 256;
    const int n0  = (wg % ntn) * 256;

    Bt += (size_t)(m0 >> 12) * (size_t)bstride;   // per-batch B panel (0 for GEMM1)

    const int NT = K >> 6;           // K-tiles (16 for K=1024); must be even >= 4

    // ---- hoisted LDS read bases (shorts). Swizzle chunk SW = quad ^ ((l16>>1)&3).
    const int SW8  = (quad ^ ((l16 >> 1) & 3)) * 8;
    const int offA = (wm * 128 + l16) * 32 + SW8;
    const int offB = 16384 + (wn * 64 + l16) * 32 + SW8;
    const short* pA0 = smem + offA;
    const short* pA1 = smem + 32768 + offA;
    const short* pB0 = smem + offB;
    const short* pB1 = smem + 32768 + offB;

    // ---- staging source pointers (advance by 64 shorts per K-tile, 128 per pair)
    const unsigned short *aS0, *aS1, *bS0, *bS1;
    {
        const int L0  = tid,        r0 = L0 >> 2, c0 = (L0 & 3) ^ ((r0 >> 1) & 3);
        const int L1  = 512 + tid,  r1 = L1 >> 2, c1 = (L1 & 3) ^ ((r1 >> 1) & 3);
        aS0 = A  + (size_t)(m0 + r0) * lda + c0 * 8;
        aS1 = A  + (size_t)(m0 + r1) * lda + c1 * 8;
        bS0 = Bt + (size_t)(n0 + r0) * ldb + c0 * 8;
        bS1 = Bt + (size_t)(n0 + r1) * ldb + c1 * 8;
    }
    const int dstoff = tid * 8;      // shorts (lane x 16B, linear gload_lds dest)

#define STAGE(BUF, ISB, H, AH) do { \
        short* d_ = smem + (BUF) * 32768 + (ISB) * 16384 + (H) * 8192 + dstoff; \
        async_copy16(((ISB) ? bS0 : aS0) + (AH) * 64 + (H) * 32, d_); \
        async_copy16(((ISB) ? bS1 : aS1) + (AH) * 64 + (H) * 32, d_ + 4096); \
    } while (0)

#define RDA4(dst, P, H, IB) do { \
        dst[0] = *(const short8*)(pA##P + ((IB) + 0) * 512 + (H) * 8192); \
        dst[1] = *(const short8*)(pA##P + ((IB) + 1) * 512 + (H) * 8192); \
        dst[2] = *(const short8*)(pA##P + ((IB) + 2) * 512 + (H) * 8192); \
        dst[3] = *(const short8*)(pA##P + ((IB) + 3) * 512 + (H) * 8192); \
    } while (0)
#define RDB2(dst, P, H, JB) do { \
        dst[0] = *(const short8*)(pB##P + ((JB) + 0) * 512 + (H) * 8192); \
        dst[1] = *(const short8*)(pB##P + ((JB) + 1) * 512 + (H) * 8192); \
    } while (0)

#define MFMA_Q(IB, JB, ak0, ak1, bk0, bk1) do { \
        _Pragma("unroll") \
        for (int i_ = 0; i_ < 4; i_++) \
            _Pragma("unroll") \
            for (int j_ = 0; j_ < 2; j_++) \
                acc[(IB) + i_][(JB) + j_] = __builtin_amdgcn_mfma_f32_16x16x32_bf16(ak0[i_], bk0[j_], acc[(IB) + i_][(JB) + j_], 0, 0, 0); \
        _Pragma("unroll") \
        for (int i_ = 0; i_ < 4; i_++) \
            _Pragma("unroll") \
            for (int j_ = 0; j_ < 2; j_++) \
                acc[(IB) + i_][(JB) + j_] = __builtin_amdgcn_mfma_f32_16x16x32_bf16(ak1[i_], bk1[j_], acc[(IB) + i_][(JB) + j_], 0, 0, 0); \
    } while (0)

#define PH_MID() do { \
        __builtin_amdgcn_s_barrier(); \
        __builtin_amdgcn_s_setprio(1); \
    } while (0)
#define PH_END() do { \
        __builtin_amdgcn_s_setprio(0); \
        __builtin_amdgcn_s_barrier(); \
    } while (0)

#define VM6   asm volatile("s_waitcnt vmcnt(6)" ::: "memory")
#define VM0   asm volatile("s_waitcnt vmcnt(0)" ::: "memory")
#define VMNOP ((void)0)

#define KTILE(P, AH, T1, T2, VMW) do { \
        short8 a0k0[4], a0k1[4], a1k0[4], a1k1[4]; \
        short8 b0k0[2], b0k1[2], b1k0[2], b1k1[2]; \
        RDA4(a0k0, P, 0, 0); RDA4(a0k1, P, 1, 0); \
        RDB2(b0k0, P, 0, 0); RDB2(b0k1, P, 1, 0); \
        if (T1) STAGE((P) ^ 1, 1, 1, (AH) + 1); \
        PH_MID(); MFMA_Q(0, 0, a0k0, a0k1, b0k0, b0k1); PH_END(); \
        RDB2(b1k0, P, 0, 2); RDB2(b1k1, P, 1, 2); \
        if (T2) STAGE(P, 1, 0, (AH) + 2); \
        PH_MID(); MFMA_Q(0, 2, a0k0, a0k1, b1k0, b1k1); PH_END(); \
        RDA4(a1k0, P, 0, 4); RDA4(a1k1, P, 1, 4); \
        if (T2) STAGE(P, 0, 0, (AH) + 2); \
        PH_MID(); MFMA_Q(4, 2, a1k0, a1k1, b1k0, b1k1); PH_END(); \
        if (T2) STAGE(P, 0, 1, (AH) + 2); \
        VMW; \
        PH_MID(); MFMA_Q(4, 0, a1k0, a1k1, b0k0, b0k1); PH_END(); \
    } while (0)

    f32x4 acc[8][4] = {};

    // ---- prologue: tile0 {A0,B0,A1,B1}; tile1 {B0,A0,A1}
    STAGE(0, 0, 0, 0); STAGE(0, 1, 0, 0); STAGE(0, 0, 1, 0); STAGE(0, 1, 1, 0);
    asm volatile("s_waitcnt vmcnt(4)" ::: "memory");
    STAGE(1, 1, 0, 1); STAGE(1, 0, 0, 1); STAGE(1, 0, 1, 1);
    asm volatile("s_waitcnt vmcnt(6)" ::: "memory");
    __builtin_amdgcn_s_barrier();

    for (int u = 0; u + 3 < NT; u += 2) {
        KTILE(0, 0, 1, 1, VM6);
        KTILE(1, 1, 1, 1, VM6);
        aS0 += 128; aS1 += 128; bS0 += 128; bS1 += 128;
    }
    KTILE(0, 0, 1, 0, VM0);
    KTILE(1, 1, 0, 0, VMNOP);

    // ---- epilogue. C/D layout: col = lane&15, row = quad*4 + r  [m89/m91]
    if (OUT_BF16) {
        __syncthreads();                               // full drain; reuse smem
        unsigned short* tile = (unsigned short*)smem;  // [128][264] padded
        unsigned short* Cp   = (unsigned short*)C;
        #pragma unroll
        for (int hm = 0; hm < 2; hm++) {
            if (wm == hm) {
                #pragma unroll
                for (int j = 0; j < 4; j++) {
                    const int tcol = wn * 64 + j * 16 + l16;
                    const float bv = bias[n0 + tcol];
                    #pragma unroll
                    for (int i = 0; i < 8; i++) {
                        const int trow = i * 16 + quad * 4;
                        #pragma unroll
                        for (int r = 0; r < 4; r++)
                            tile[(trow + r) * 264 + tcol] = f2bf(acc[i][j][r] + bv);
                    }
                }
            }
            __syncthreads();
            #pragma unroll
            for (int pp = 0; pp < 8; pp++) {
                const int row = pp * 16 + (tid >> 5);
                const int ch  = tid & 31;
                short8 v = *(const short8*)&tile[row * 264 + ch * 8];
                *(short8*)&Cp[(size_t)(m0 + hm * 128 + row) * ldc + n0 + ch * 8] = v;
            }
            __syncthreads();
        }
    } else {
        // fp32 out with per-row rq scaling: y = rq[row]*acc + bias.
        // Restage through LDS ([128][256] f32 = exactly 128 KiB) so global
        // stores are 1 KiB contiguous per wave (vs 64B segments direct).
        // XOR bit-4 (64B) swizzle keyed on row quad -> 2-way-free LDS writes,
        // contiguity-preserving for float4 reads.
        __syncthreads();
        float* ftile = (float*)smem;
        float* Cp = (float*)C;
        #pragma unroll
        for (int hm = 0; hm < 2; hm++) {
            if (wm == hm) {
                #pragma unroll
                for (int j = 0; j < 4; j++) {
                    const int tcol = wn * 64 + j * 16 + l16;
                    const float bv = bias[n0 + tcol];
                    #pragma unroll
                    for (int i = 0; i < 8; i++) {
                        const int trow = i * 16 + quad * 4;
                        const int cs = tcol ^ ((quad & 1) << 4);
                        #pragma unroll
                        for (int r = 0; r < 4; r++) {
                            const float rqv = rq[m0 + hm * 128 + trow + r];
                            ftile[(trow + r) * 256 + cs] = acc[i][j][r] * rqv + bv;
                        }
                    }
                }
            }
            __syncthreads();
            #pragma unroll
            for (int p = 0; p < 16; p++) {
                const int row = p * 8 + (tid >> 6);
                const int c4  = (tid & 63) * 4;
                const int cr  = c4 ^ (((row >> 2) & 1) << 4);
                float4 v = *(const float4*)&ftile[row * 256 + cr];
                *(float4*)&Cp[(size_t)(m0 + hm * 128 + row) * ldc + n0 + c4] = v;
            }
            __syncthreads();
        }
    }
#undef STAGE
#undef RDA4
#undef RDB2
#undef MFMA_Q
#undef PH_MID
#undef PH_END
#undef VM6
#undef VM0
#undef VMNOP
#undef KTILE
}

// ---------- per-row q/k norms + kv partials (NO atomics) ----------
__global__ __launch_bounds__(256) void norm_kv(const unsigned short* __restrict__ qkv,
                                               float* __restrict__ rnq,
                                               float* __restrict__ part) {
    __shared__ float kvbuf[4][1024];   // 16 KB, one slice per wave
    const int tid = threadIdx.x, lane = tid & 63, wv = tid >> 6;

    const int row0 = blockIdx.x * 16 + wv * 4;
    float a[2][8] = {};

    #pragma unroll
    for (int rr = 0; rr < 4; rr++) {
        const size_t base = (size_t)(row0 + rr) * 3072;
        float q2 = 0.f;
        #pragma unroll
        for (int c = 0; c < 2; c++) {
            short8 qu = *(const short8*)&qkv[base + c * 512 + lane * 8];
            #pragma unroll
            for (int j = 0; j < 8; j++) {
                float v = bf2f((unsigned short)qu[j]);
                q2 += v * v;
            }
        }
        #pragma unroll
        for (int m = 32; m; m >>= 1) q2 += __shfl_xor(q2, m, 64);
        if (lane == 0) rnq[row0 + rr] = rsqrtf(q2);

        float k2 = 0.f;
        float kf[2][8];
        #pragma unroll
        for (int c = 0; c < 2; c++) {
            short8 ku = *(const short8*)&qkv[base + 1024 + c * 512 + lane * 8];
            #pragma unroll
            for (int j = 0; j < 8; j++) {
                kf[c][j] = bf2f((unsigned short)ku[j]);
                k2 += kf[c][j] * kf[c][j];
            }
        }
        #pragma unroll
        for (int m = 32; m; m >>= 1) k2 += __shfl_xor(k2, m, 64);
        const float rk = rsqrtf(k2);

        #pragma unroll
        for (int c = 0; c < 2; c++) {
            short8 vu = *(const short8*)&qkv[base + 2048 + c * 512 + lane * 8];
            #pragma unroll
            for (int j = 0; j < 8; j++)
                a[c][j] += kf[c][j] * rk * bf2f((unsigned short)vu[j]);
        }
    }
    #pragma unroll
    for (int c = 0; c < 2; c++) {
        *(float4*)&kvbuf[wv][c * 512 + lane * 8]     = make_float4(a[c][0], a[c][1], a[c][2], a[c][3]);
        *(float4*)&kvbuf[wv][c * 512 + lane * 8 + 4] = make_float4(a[c][4], a[c][5], a[c][6], a[c][7]);
    }
    __syncthreads();
    float4 s = *(const float4*)&kvbuf[0][tid * 4];
    #pragma unroll
    for (int w = 1; w < 4; w++) {
        float4 t = *(const float4*)&kvbuf[w][tid * 4];
        s.x += t.x; s.y += t.y; s.z += t.z; s.w += t.w;
    }
    *(float4*)&part[(size_t)blockIdx.x * 1024 + tid * 4] = s;
}

// ---------- reduce 256 partials per batch -> kv[4][1024] ----------
// 128 blocks: b = bid>>5, 32-col chunk (bid&31)*32; 8 groups of 32 lanes each
// sum 32 partial rows; LDS combine.
__global__ __launch_bounds__(256) void reduce_kv(const float* __restrict__ part,
                                                 float* __restrict__ kv) {
    __shared__ float red[8][32];
    const int b   = blockIdx.x >> 5;
    const int col = (blockIdx.x & 31) * 32 + (threadIdx.x & 31);
    const int g   = threadIdx.x >> 5;    // 0..7
    float s = 0.f;
    #pragma unroll 4
    for (int r = g * 32; r < g * 32 + 32; r++)
        s += part[(size_t)(b * 256 + r) * 1024 + col];
    red[g][threadIdx.x & 31] = s;
    __syncthreads();
    if (g == 0) {
        float t = 0.f;
        #pragma unroll
        for (int w = 0; w < 8; w++) t += red[w][threadIdx.x & 31];
        kv[b * 1024 + col] = t;
    }
}

// ---------- WoutS[b][n][k] = WoutT[n][k] * kv[b][k]  (bf16, per-batch B) ----------
__global__ __launch_bounds__(256) void scale_w(const unsigned short* __restrict__ WoutT,
                                               const float* __restrict__ kv,
                                               unsigned short* __restrict__ WoutS) {
    const int b   = blockIdx.x >> 9;                        // 2048 blocks: 512/batch
    const int idx = (blockIdx.x & 511) * 256 + threadIdx.x; // 131072 short8 per batch
    const int n   = idx >> 7;
    const int k8  = (idx & 127) * 8;
    short8 w = *(const short8*)&WoutT[n * 1024 + k8];
    float4 k0 = *(const float4*)&kv[b * 1024 + k8];
    float4 k1 = *(const float4*)&kv[b * 1024 + k8 + 4];
    short8 o;
    o[0] = (short)f2bf(bf2f((unsigned short)w[0]) * k0.x);
    o[1] = (short)f2bf(bf2f((unsigned short)w[1]) * k0.y);
    o[2] = (short)f2bf(bf2f((unsigned short)w[2]) * k0.z);
    o[3] = (short)f2bf(bf2f((unsigned short)w[3]) * k0.w);
    o[4] = (short)f2bf(bf2f((unsigned short)w[4]) * k1.x);
    o[5] = (short)f2bf(bf2f((unsigned short)w[5]) * k1.y);
    o[6] = (short)f2bf(bf2f((unsigned short)w[6]) * k1.z);
    o[7] = (short)f2bf(bf2f((unsigned short)w[7]) * k1.w);
    *(short8*)&WoutS[((size_t)b << 20) + n * 1024 + k8] = o;
}

extern "C" void kernel_launch(void* const* d_in, const int* in_sizes, int n_in,
                              void* d_out, int out_size, void* d_ws, size_t ws_size,
                              hipStream_t stream) {
    const float* x    = (const float*)d_in[0];   // (4,4096,1024)
    const float* Wqkv = (const float*)d_in[1];   // (1024,3072)
    const float* bqkv = (const float*)d_in[2];   // (3072)
    const float* Wout = (const float*)d_in[3];   // (1024,1024)
    const float* bout = (const float*)d_in[4];   // (1024)
    float* out = (float*)d_out;                  // (4,4096,1024) fp32

    // workspace layout (~136 MB)
    char* ws = (char*)d_ws;
    unsigned short* x_bf  = (unsigned short*)(ws + 0);           // 32 MB (dead after GEMM1)
    unsigned short* WqkvT = (unsigned short*)(ws + 33554432);    // 6 MB
    unsigned short* WoutT = (unsigned short*)(ws + 39845888);    // 2 MB
    unsigned short* qkv   = (unsigned short*)(ws + 41943040);    // 96 MB
    float* rnq            = (float*)(ws + 142606336);            // 64 KB
    float* kv             = (float*)(ws + 142671872);            // 16 KB
    float* part           = (float*)(ws + 0);                    // 4 MB (x_bf region, dead)
    unsigned short* WoutS = (unsigned short*)(ws + 8388608);     // 8 MB (x_bf region, dead)

    // fused: x conversion + both weight transposes
    prep<<<12288, 256, 0, stream>>>(x, Wqkv, Wout, x_bf, WqkvT, WoutT);

    // qkv = x @ Wqkv + bqkv   (M=16384, N=3072, K=1024) -> bf16; 64x12 = 768 tiles
    gemm_bf16<true><<<768, 512, 0, stream>>>(x_bf, 1024, WqkvT, 1024, bqkv, nullptr,
                                             (void*)qkv, 3072, 1024, 12, 0);

    norm_kv<<<1024, 256, 0, stream>>>(qkv, rnq, part);
    reduce_kv<<<128, 256, 0, stream>>>(part, kv);

    // fold kv into Wout (per batch); rq folds into GEMM2's epilogue
    scale_w<<<2048, 256, 0, stream>>>(WoutT, kv, WoutS);

    // y[b] = rq * (q[b] @ (Wout .* kv[b])) + bout  (M=16384, N=1024, K=1024) -> fp32
    gemm_bf16<false><<<256, 512, 0, stream>>>(qkv, 3072, WoutS, 1024, bout, rnq,
                                              (void*)out, 1024, 1024, 4, 1 << 20);
}